// Round 3
// baseline (1559.581 us; speedup 1.0000x reference)
//
#include <hip/hip_runtime.h>

#define N_NODESC 100000
#define N_EDGESC 300000
#define N_GRAPHSC 4000
#define IN_F 16
#define HID 256
#define RCHUNK 32

typedef __attribute__((ext_vector_type(8))) short short8v;   // 8 bf16 (4 VGPRs)
typedef __attribute__((ext_vector_type(4))) float f32x4;     // 4 fp32

// bf16 round-to-nearest-even, returned as fp32-aligned high bits
__device__ __forceinline__ unsigned bf16rne(float v) {
  unsigned u = __float_as_uint(v);
  return (u + 0x7fffu + ((u >> 16) & 1u)) & 0xffff0000u;
}

// ---------------- degree / norm / CSR build ----------------

__global__ __launch_bounds__(256) void k_degrees(const int* __restrict__ src,
                                                 const int* __restrict__ dst,
                                                 int* __restrict__ outd,
                                                 int* __restrict__ ind) {
  int e = blockIdx.x * blockDim.x + threadIdx.x;
  if (e < N_EDGESC) {
    atomicAdd(&outd[src[e]], 1);
    atomicAdd(&ind[dst[e]], 1);
  }
}

__global__ __launch_bounds__(256) void k_norms(const int* __restrict__ outd,
                                               const int* __restrict__ ind,
                                               float* __restrict__ onorm,
                                               float* __restrict__ inorm) {
  int i = blockIdx.x * blockDim.x + threadIdx.x;
  if (i < N_NODESC) {
    onorm[i] = rsqrtf((float)max(outd[i], 1));
    inorm[i] = rsqrtf((float)max(ind[i], 1));
  }
}

// single-block exclusive scan of in-degrees -> CSR offsets
__global__ __launch_bounds__(1024) void k_scan(const int* __restrict__ ind,
                                               int* __restrict__ offs) {
  __shared__ int sh[1024];
  const int n = N_NODESC;
  int t = threadIdx.x;
  int chunk = (n + 1023) >> 10;
  int b = t * chunk;
  int e = min(b + chunk, n);
  int s = 0;
  for (int i = b; i < e; ++i) s += ind[i];
  sh[t] = s;
  __syncthreads();
  for (int o = 1; o < 1024; o <<= 1) {
    int x = (t >= o) ? sh[t - o] : 0;
    __syncthreads();
    sh[t] += x;
    __syncthreads();
  }
  int pre = sh[t] - s;
  for (int i = b; i < e; ++i) {
    offs[i] = pre;
    pre += ind[i];
  }
  if (t == 1023) offs[n] = sh[1023];
}

__global__ __launch_bounds__(256) void k_fill(const int* __restrict__ src,
                                              const int* __restrict__ dst,
                                              const int* __restrict__ offs,
                                              int* __restrict__ cursor,
                                              int* __restrict__ csr) {
  int e = blockIdx.x * blockDim.x + threadIdx.x;
  if (e < N_EDGESC) {
    int d = dst[e];
    int p = offs[d] + atomicAdd(&cursor[d], 1);
    csr[p] = src[e];
  }
}

// ---------------- layer 1: 16-d aggregation + 16x256 matmul ----------------

__global__ __launch_bounds__(256) void k_agg16(const float* __restrict__ feats,
                                               const int* __restrict__ offs,
                                               const int* __restrict__ csr,
                                               const float* __restrict__ onorm,
                                               const float* __restrict__ inorm,
                                               float* __restrict__ agg1) {
  int gid = blockIdx.x * blockDim.x + threadIdx.x;
  int node = gid >> 4;
  if (node >= N_NODESC) return;
  int f = gid & 15;
  int b = offs[node], e = offs[node + 1];
  float acc = 0.f;
  for (int k = b; k < e; ++k) {
    int s = csr[k];
    acc = fmaf(feats[s * IN_F + f], onorm[s], acc);
  }
  agg1[(size_t)node * IN_F + f] = acc * inorm[node];
}

__global__ __launch_bounds__(256) void k_mm16(const float* __restrict__ agg1,
                                              const float* __restrict__ W,
                                              const float* __restrict__ bias,
                                              float* __restrict__ out) {
  __shared__ float Ws[IN_F * HID];
  __shared__ float bs[HID];
  int t = threadIdx.x;
  for (int i = t; i < IN_F * HID; i += 256) Ws[i] = W[i];
  bs[t] = bias[t];
  __syncthreads();
  for (int node = blockIdx.x; node < N_NODESC; node += gridDim.x) {
    float a[IN_F];
#pragma unroll
    for (int k = 0; k < IN_F; ++k) a[k] = agg1[(size_t)node * IN_F + k];
    float acc = bs[t];
#pragma unroll
    for (int k = 0; k < IN_F; ++k) acc = fmaf(a[k], Ws[k * HID + t], acc);
    out[(size_t)node * HID + t] = acc;
  }
}

// ---------------- 256-d aggregation: one wave per node, bf16-split output ----------------

__global__ __launch_bounds__(256) void k_agg256(const float* __restrict__ h,
                                                const int* __restrict__ offs,
                                                const int* __restrict__ csr,
                                                const float* __restrict__ onorm,
                                                const float* __restrict__ inorm,
                                                short* __restrict__ aggh,
                                                short* __restrict__ aggl) {
  int wid = (int)((blockIdx.x * (size_t)blockDim.x + threadIdx.x) >> 6);
  int lane = threadIdx.x & 63;
  if (wid >= N_NODESC) return;
  int b = offs[wid], e = offs[wid + 1];
  const float4* hp = (const float4*)h;
  float4 acc = make_float4(0.f, 0.f, 0.f, 0.f);
  for (int k = b; k < e; ++k) {
    int s = csr[k];
    float w = onorm[s];
    float4 v = hp[(size_t)s * 64 + lane];
    acc.x = fmaf(v.x, w, acc.x);
    acc.y = fmaf(v.y, w, acc.y);
    acc.z = fmaf(v.z, w, acc.z);
    acc.w = fmaf(v.w, w, acc.w);
  }
  float wi = inorm[wid];
  float v[4] = {acc.x * wi, acc.y * wi, acc.z * wi, acc.w * wi};
  unsigned hb[4], lb[4];
#pragma unroll
  for (int j = 0; j < 4; ++j) {
    hb[j] = bf16rne(v[j]);
    float res = v[j] - __uint_as_float(hb[j]);
    lb[j] = bf16rne(res);
  }
  uint2 ph = make_uint2((hb[0] >> 16) | hb[1], (hb[2] >> 16) | hb[3]);
  uint2 pl = make_uint2((lb[0] >> 16) | lb[1], (lb[2] >> 16) | lb[3]);
  ((uint2*)aggh)[(size_t)wid * 64 + lane] = ph;
  ((uint2*)aggl)[(size_t)wid * 64 + lane] = pl;
}

// ---------------- W transpose + bf16 split: Wt[n][k] ----------------

__global__ __launch_bounds__(256) void k_wsplit(const float* __restrict__ W,
                                                short* __restrict__ Wth,
                                                short* __restrict__ Wtl) {
  int i = blockIdx.x * blockDim.x + threadIdx.x;  // i = k*256 + n
  if (i >= HID * HID) return;
  int k = i >> 8, n = i & 255;
  float v = W[i];
  unsigned hb = bf16rne(v);
  float res = v - __uint_as_float(hb);
  unsigned lb = bf16rne(res);
  Wth[(size_t)n * HID + k] = (short)(hb >> 16);
  Wtl[(size_t)n * HID + k] = (short)(lb >> 16);
}

// ---------------- MFMA GEMM: C[M x 256] = A @ W + bias, split-bf16 x3 ----------------
// Block = 256 thr = 4 waves; each wave owns 32 rows x 256 cols.
// Fragment layouts (gfx950, verified m89/m91/m97):
//   A: lane l holds A[l&15][8*(l>>4)+e], e=0..7 contiguous  (b128 load)
//   B: lane l holds B[8*(l>>4)+e][l&15]  -> from Wt[n][k] row-contiguous
//   C/D: col = lane&15, row = (lane>>4)*4 + reg

__global__ __launch_bounds__(256) void k_gemm_mfma(
    const short* __restrict__ Ah, const short* __restrict__ Al,
    const short* __restrict__ Wth, const short* __restrict__ Wtl,
    const float* __restrict__ bias, float* __restrict__ C, int M) {
  int t = threadIdx.x;
  int wave = t >> 6, lane = t & 63;
  int m0 = blockIdx.x * 128 + wave * 32;
  int lr = lane & 15;
  int lk = (lane >> 4) * 8;

  f32x4 acc[2][16];
#pragma unroll
  for (int mf = 0; mf < 2; ++mf)
#pragma unroll
    for (int nf = 0; nf < 16; ++nf) acc[mf][nf] = (f32x4){0.f, 0.f, 0.f, 0.f};

  for (int k0 = 0; k0 < HID; k0 += 32) {
    short8v ah[2], al[2];
#pragma unroll
    for (int mf = 0; mf < 2; ++mf) {
      int row = m0 + mf * 16 + lr;
      row = min(row, M - 1);  // clamp: loads safe, writes guarded below
      size_t o = (size_t)row * HID + k0 + lk;
      ah[mf] = *(const short8v*)(Ah + o);
      al[mf] = *(const short8v*)(Al + o);
    }
#pragma unroll 4
    for (int nf = 0; nf < 16; ++nf) {
      size_t wo = (size_t)(nf * 16 + lr) * HID + k0 + lk;
      short8v wh = *(const short8v*)(Wth + wo);
      short8v wl = *(const short8v*)(Wtl + wo);
#pragma unroll
      for (int mf = 0; mf < 2; ++mf) {
        acc[mf][nf] = __builtin_amdgcn_mfma_f32_16x16x32_bf16(ah[mf], wh, acc[mf][nf], 0, 0, 0);
        acc[mf][nf] = __builtin_amdgcn_mfma_f32_16x16x32_bf16(al[mf], wh, acc[mf][nf], 0, 0, 0);
        acc[mf][nf] = __builtin_amdgcn_mfma_f32_16x16x32_bf16(ah[mf], wl, acc[mf][nf], 0, 0, 0);
      }
    }
  }

  int cr = (lane >> 4) * 4;
#pragma unroll
  for (int mf = 0; mf < 2; ++mf) {
#pragma unroll
    for (int nf = 0; nf < 16; ++nf) {
      float bv = bias[nf * 16 + lr];
      f32x4 v = acc[mf][nf];
#pragma unroll
      for (int r = 0; r < 4; ++r) {
        int row = m0 + mf * 16 + cr + r;
        if (row < M) C[(size_t)row * HID + nf * 16 + lr] = v[r] + bv;
      }
    }
  }
}

// ---------------- readout: sigmoid-weighted sum + segment max ----------------

__device__ __forceinline__ unsigned fkey(float f) {
  unsigned u = __float_as_uint(f);
  return (u & 0x80000000u) ? ~u : (u | 0x80000000u);
}

__device__ __forceinline__ void flush_group(int g, int lane, const float4& s,
                                            const uint4& mk, float* __restrict__ out,
                                            unsigned* __restrict__ mkeys) {
  float* hp = out + (size_t)g * 512 + (lane << 2);
  atomicAdd(hp + 0, s.x);
  atomicAdd(hp + 1, s.y);
  atomicAdd(hp + 2, s.z);
  atomicAdd(hp + 3, s.w);
  unsigned* mp = mkeys + ((size_t)g << 8) + (lane << 2);
  atomicMax(mp + 0, mk.x);
  atomicMax(mp + 1, mk.y);
  atomicMax(mp + 2, mk.z);
  atomicMax(mp + 3, mk.w);
}

__global__ __launch_bounds__(256) void k_readout(const float* __restrict__ h,
                                                 const int* __restrict__ gids,
                                                 const float* __restrict__ w_atom,
                                                 const float* __restrict__ b_atom,
                                                 float* __restrict__ out,
                                                 unsigned* __restrict__ mkeys) {
  int wid = (int)((blockIdx.x * (size_t)blockDim.x + threadIdx.x) >> 6);
  int lane = threadIdx.x & 63;
  int n0 = wid * RCHUNK;
  if (n0 >= N_NODESC) return;
  int n1 = min(n0 + RCHUNK, N_NODESC);
  float4 wa = ((const float4*)w_atom)[lane];
  float ba = b_atom[0];
  float4 s = make_float4(0.f, 0.f, 0.f, 0.f);
  uint4 mk = make_uint4(0u, 0u, 0u, 0u);
  int cur = gids[n0];
  for (int i = n0; i < n1; ++i) {
    int g = gids[i];
    if (g != cur) {
      flush_group(cur, lane, s, mk, out, mkeys);
      s = make_float4(0.f, 0.f, 0.f, 0.f);
      mk = make_uint4(0u, 0u, 0u, 0u);
      cur = g;
    }
    float4 v = ((const float4*)h)[(size_t)i * 64 + lane];
    float d = fmaf(v.x, wa.x, fmaf(v.y, wa.y, fmaf(v.z, wa.z, v.w * wa.w)));
#pragma unroll
    for (int o = 32; o > 0; o >>= 1) d += __shfl_xor(d, o, 64);
    float wgt = 1.0f / (1.0f + expf(-(d + ba)));
    s.x = fmaf(v.x, wgt, s.x);
    s.y = fmaf(v.y, wgt, s.y);
    s.z = fmaf(v.z, wgt, s.z);
    s.w = fmaf(v.w, wgt, s.w);
    mk.x = max(mk.x, fkey(v.x));
    mk.y = max(mk.y, fkey(v.y));
    mk.z = max(mk.z, fkey(v.z));
    mk.w = max(mk.w, fkey(v.w));
  }
  flush_group(cur, lane, s, mk, out, mkeys);
}

__global__ __launch_bounds__(256) void k_finalize(const unsigned* __restrict__ mkeys,
                                                  float* __restrict__ out) {
  int i = blockIdx.x * blockDim.x + threadIdx.x;
  if (i >= N_GRAPHSC * HID) return;
  int g = i >> 8, c = i & 255;
  unsigned k = mkeys[i];
  float f = 0.0f;
  if (k != 0u) f = (k & 0x80000000u) ? __uint_as_float(k ^ 0x80000000u) : __uint_as_float(~k);
  out[(size_t)g * 512 + 256 + c] = f;
}

// ---------------- predictor MLP ----------------

__global__ __launch_bounds__(256) void k_pred(const float* __restrict__ hg,
                                              const float* __restrict__ P1,
                                              const float* __restrict__ pb1,
                                              const float* __restrict__ P2,
                                              const float* __restrict__ pb2,
                                              float* __restrict__ pred) {
  __shared__ float P1s[32 * 256];
  __shared__ float hgt[32 * 16];
  int t = threadIdx.x;
  int g0 = blockIdx.x * 16;
  int tx = t & 63;
  int tg = t >> 6;
  float acc[4][4];
#pragma unroll
  for (int a = 0; a < 4; ++a)
#pragma unroll
    for (int b = 0; b < 4; ++b) acc[a][b] = 0.f;

  for (int kc = 0; kc < 512; kc += 32) {
    const float4* srcp = (const float4*)(P1 + (size_t)kc * 256);
    float4* dstp = (float4*)P1s;
    for (int i = t; i < 2048; i += 256) dstp[i] = srcp[i];
    {
      int g = t & 15, kk = t >> 4;
      const float* hrow = hg + (size_t)(g0 + g) * 512 + kc;
#pragma unroll
      for (int j = 0; j < 2; ++j) hgt[(kk * 2 + j) * 16 + g] = hrow[kk * 2 + j];
    }
    __syncthreads();
#pragma unroll 8
    for (int k = 0; k < 32; ++k) {
      float4 pv = *(const float4*)&P1s[k * 256 + (tx << 2)];
      float4 hv = *(const float4*)&hgt[(k << 4) + (tg << 2)];
      acc[0][0] = fmaf(hv.x, pv.x, acc[0][0]);
      acc[0][1] = fmaf(hv.x, pv.y, acc[0][1]);
      acc[0][2] = fmaf(hv.x, pv.z, acc[0][2]);
      acc[0][3] = fmaf(hv.x, pv.w, acc[0][3]);
      acc[1][0] = fmaf(hv.y, pv.x, acc[1][0]);
      acc[1][1] = fmaf(hv.y, pv.y, acc[1][1]);
      acc[1][2] = fmaf(hv.y, pv.z, acc[1][2]);
      acc[1][3] = fmaf(hv.y, pv.w, acc[1][3]);
      acc[2][0] = fmaf(hv.z, pv.x, acc[2][0]);
      acc[2][1] = fmaf(hv.z, pv.y, acc[2][1]);
      acc[2][2] = fmaf(hv.z, pv.z, acc[2][2]);
      acc[2][3] = fmaf(hv.z, pv.w, acc[2][3]);
      acc[3][0] = fmaf(hv.w, pv.x, acc[3][0]);
      acc[3][1] = fmaf(hv.w, pv.y, acc[3][1]);
      acc[3][2] = fmaf(hv.w, pv.z, acc[3][2]);
      acc[3][3] = fmaf(hv.w, pv.w, acc[3][3]);
    }
    __syncthreads();
  }

  float4 b1v = *(const float4*)(pb1 + (tx << 2));
  float4 p2v = *(const float4*)(P2 + (tx << 2));
  float pb2v = pb2[0];
#pragma unroll
  for (int g = 0; g < 4; ++g) {
    float r = fmaxf(acc[g][0] + b1v.x, 0.f) * p2v.x +
              fmaxf(acc[g][1] + b1v.y, 0.f) * p2v.y +
              fmaxf(acc[g][2] + b1v.z, 0.f) * p2v.z +
              fmaxf(acc[g][3] + b1v.w, 0.f) * p2v.w;
#pragma unroll
    for (int o = 32; o > 0; o >>= 1) r += __shfl_xor(r, o, 64);
    if (tx == 0) pred[g0 + (tg << 2) + g] = r + pb2v;
  }
}

// ---------------- host orchestration ----------------

extern "C" void kernel_launch(void* const* d_in, const int* in_sizes, int n_in,
                              void* d_out, int out_size, void* d_ws, size_t ws_size,
                              hipStream_t stream) {
  const float* feats = (const float*)d_in[0];
  const int* src = (const int*)d_in[1];
  const int* dst = (const int*)d_in[2];
  const int* gids = (const int*)d_in[3];
  const float* W1 = (const float*)d_in[4];
  const float* b1 = (const float*)d_in[5];
  const float* W2 = (const float*)d_in[6];
  const float* b2 = (const float*)d_in[7];
  const float* W3 = (const float*)d_in[8];
  const float* b3 = (const float*)d_in[9];
  const float* w_atom = (const float*)d_in[10];
  const float* b_atom = (const float*)d_in[11];
  const float* P1 = (const float*)d_in[12];
  const float* pb1 = (const float*)d_in[13];
  const float* P2 = (const float*)d_in[14];
  const float* pb2 = (const float*)d_in[15];
  float* out = (float*)d_out;

  char* base = (char*)d_ws;
  size_t off = 0;
  auto alloc = [&](size_t bytes) -> void* {
    void* p = base + off;
    off = (off + bytes + 511) & ~(size_t)511;
    return p;
  };
  int* outd = (int*)alloc((size_t)N_NODESC * 4);
  int* ind = (int*)alloc((size_t)N_NODESC * 4);
  float* onorm = (float*)alloc((size_t)N_NODESC * 4);
  float* inorm = (float*)alloc((size_t)N_NODESC * 4);
  int* offs = (int*)alloc((size_t)(N_NODESC + 1) * 4);
  int* cursor = (int*)alloc((size_t)N_NODESC * 4);
  int* csr = (int*)alloc((size_t)N_EDGESC * 4);
  float* agg1 = (float*)alloc((size_t)N_NODESC * IN_F * 4);
  float* bufA = (float*)alloc((size_t)N_NODESC * HID * 4);
  short* aggh = (short*)alloc((size_t)N_NODESC * HID * 2);
  short* aggl = (short*)alloc((size_t)N_NODESC * HID * 2);
  short* Wth2 = (short*)alloc((size_t)HID * HID * 2);
  short* Wtl2 = (short*)alloc((size_t)HID * HID * 2);
  short* Wth3 = (short*)alloc((size_t)HID * HID * 2);
  short* Wtl3 = (short*)alloc((size_t)HID * HID * 2);
  unsigned* mkeys = (unsigned*)alloc((size_t)N_GRAPHSC * HID * 4);

  hipMemsetAsync(outd, 0, (size_t)N_NODESC * 4, stream);
  hipMemsetAsync(ind, 0, (size_t)N_NODESC * 4, stream);
  hipMemsetAsync(cursor, 0, (size_t)N_NODESC * 4, stream);
  hipMemsetAsync(mkeys, 0, (size_t)N_GRAPHSC * HID * 4, stream);
  hipMemsetAsync(out, 0, (size_t)out_size * 4, stream);

  k_degrees<<<(N_EDGESC + 255) / 256, 256, 0, stream>>>(src, dst, outd, ind);
  k_norms<<<(N_NODESC + 255) / 256, 256, 0, stream>>>(outd, ind, onorm, inorm);
  k_scan<<<1, 1024, 0, stream>>>(ind, offs);
  k_fill<<<(N_EDGESC + 255) / 256, 256, 0, stream>>>(src, dst, offs, cursor, csr);

  // W splits (independent of graph pipeline)
  k_wsplit<<<(HID * HID + 255) / 256, 256, 0, stream>>>(W2, Wth2, Wtl2);
  k_wsplit<<<(HID * HID + 255) / 256, 256, 0, stream>>>(W3, Wth3, Wtl3);

  // layer 1
  k_agg16<<<(N_NODESC * IN_F + 255) / 256, 256, 0, stream>>>(feats, offs, csr, onorm,
                                                             inorm, agg1);
  k_mm16<<<2048, 256, 0, stream>>>(agg1, W1, b1, bufA);

  // layer 2
  k_agg256<<<(N_NODESC * 64 + 255) / 256, 256, 0, stream>>>(bufA, offs, csr, onorm,
                                                            inorm, aggh, aggl);
  k_gemm_mfma<<<(N_NODESC + 127) / 128, 256, 0, stream>>>(aggh, aggl, Wth2, Wtl2, b2,
                                                          bufA, N_NODESC);
  // layer 3
  k_agg256<<<(N_NODESC * 64 + 255) / 256, 256, 0, stream>>>(bufA, offs, csr, onorm,
                                                            inorm, aggh, aggl);
  k_gemm_mfma<<<(N_NODESC + 127) / 128, 256, 0, stream>>>(aggh, aggl, Wth3, Wtl3, b3,
                                                          bufA, N_NODESC);

  // readout + predictor
  int rwaves = (N_NODESC + RCHUNK - 1) / RCHUNK;
  k_readout<<<(rwaves * 64 + 255) / 256, 256, 0, stream>>>(bufA, gids, w_atom, b_atom,
                                                           out, mkeys);
  k_finalize<<<(N_GRAPHSC * HID + 255) / 256, 256, 0, stream>>>(mkeys, out);
  k_pred<<<N_GRAPHSC / 16, 256, 0, stream>>>(out, P1, pb1, P2, pb2,
                                             out + (size_t)N_GRAPHSC * 512);
}

// Round 8
// 986.442 us; speedup vs baseline: 1.5810x; 1.5810x over previous
//
#include <hip/hip_runtime.h>

#define N_NODESC 100000
#define N_EDGESC 300000
#define N_GRAPHSC 4000
#define IN_F 16
#define HID 256
#define RCHUNK 32

typedef __attribute__((ext_vector_type(8))) short short8v;   // 8 bf16 (4 VGPRs)
typedef __attribute__((ext_vector_type(4))) float f32x4;     // 4 fp32

// bf16 round-to-nearest-even, returned as fp32-aligned high bits
__device__ __forceinline__ unsigned bf16rne(float v) {
  unsigned u = __float_as_uint(v);
  return (u + 0x7fffu + ((u >> 16) & 1u)) & 0xffff0000u;
}

// ---------------- degree / norm / CSR build ----------------

__global__ __launch_bounds__(256) void k_degrees(const int* __restrict__ src,
                                                 const int* __restrict__ dst,
                                                 int* __restrict__ outd,
                                                 int* __restrict__ ind) {
  int e = blockIdx.x * blockDim.x + threadIdx.x;
  if (e < N_EDGESC) {
    atomicAdd(&outd[src[e]], 1);
    atomicAdd(&ind[dst[e]], 1);
  }
}

__global__ __launch_bounds__(256) void k_norms(const int* __restrict__ outd,
                                               const int* __restrict__ ind,
                                               float* __restrict__ onorm,
                                               float* __restrict__ inorm) {
  int i = blockIdx.x * blockDim.x + threadIdx.x;
  if (i < N_NODESC) {
    onorm[i] = rsqrtf((float)max(outd[i], 1));
    inorm[i] = rsqrtf((float)max(ind[i], 1));
  }
}

// single-block exclusive scan of in-degrees -> CSR offsets
__global__ __launch_bounds__(1024) void k_scan(const int* __restrict__ ind,
                                               int* __restrict__ offs) {
  __shared__ int sh[1024];
  const int n = N_NODESC;
  int t = threadIdx.x;
  int chunk = (n + 1023) >> 10;
  int b = t * chunk;
  int e = min(b + chunk, n);
  int s = 0;
  for (int i = b; i < e; ++i) s += ind[i];
  sh[t] = s;
  __syncthreads();
  for (int o = 1; o < 1024; o <<= 1) {
    int x = (t >= o) ? sh[t - o] : 0;
    __syncthreads();
    sh[t] += x;
    __syncthreads();
  }
  int pre = sh[t] - s;
  for (int i = b; i < e; ++i) {
    offs[i] = pre;
    pre += ind[i];
  }
  if (t == 1023) offs[n] = sh[1023];
}

__global__ __launch_bounds__(256) void k_fill(const int* __restrict__ src,
                                              const int* __restrict__ dst,
                                              const int* __restrict__ offs,
                                              int* __restrict__ cursor,
                                              int* __restrict__ csr) {
  int e = blockIdx.x * blockDim.x + threadIdx.x;
  if (e < N_EDGESC) {
    int d = dst[e];
    int p = offs[d] + atomicAdd(&cursor[d], 1);
    csr[p] = src[e];
  }
}

// ---------------- layer 1: 16-d aggregation + 16x256 matmul ----------------

__global__ __launch_bounds__(256) void k_agg16(const float* __restrict__ feats,
                                               const int* __restrict__ offs,
                                               const int* __restrict__ csr,
                                               const float* __restrict__ onorm,
                                               const float* __restrict__ inorm,
                                               float* __restrict__ agg1) {
  int gid = blockIdx.x * blockDim.x + threadIdx.x;
  int node = gid >> 4;
  if (node >= N_NODESC) return;
  int f = gid & 15;
  int b = offs[node], e = offs[node + 1];
  float acc = 0.f;
  for (int k = b; k < e; ++k) {
    int s = csr[k];
    acc = fmaf(feats[s * IN_F + f], onorm[s], acc);
  }
  agg1[(size_t)node * IN_F + f] = acc * inorm[node];
}

__global__ __launch_bounds__(256) void k_mm16(const float* __restrict__ agg1,
                                              const float* __restrict__ W,
                                              const float* __restrict__ bias,
                                              float* __restrict__ out) {
  __shared__ float Ws[IN_F * HID];
  __shared__ float bs[HID];
  int t = threadIdx.x;
  for (int i = t; i < IN_F * HID; i += 256) Ws[i] = W[i];
  bs[t] = bias[t];
  __syncthreads();
  for (int node = blockIdx.x; node < N_NODESC; node += gridDim.x) {
    float a[IN_F];
#pragma unroll
    for (int k = 0; k < IN_F; ++k) a[k] = agg1[(size_t)node * IN_F + k];
    float acc = bs[t];
#pragma unroll
    for (int k = 0; k < IN_F; ++k) acc = fmaf(a[k], Ws[k * HID + t], acc);
    out[(size_t)node * HID + t] = acc;
  }
}

// ---------------- 256-d aggregation: one wave per node, bf16-split output ----------------

__global__ __launch_bounds__(256) void k_agg256(const float* __restrict__ h,
                                                const int* __restrict__ offs,
                                                const int* __restrict__ csr,
                                                const float* __restrict__ onorm,
                                                const float* __restrict__ inorm,
                                                short* __restrict__ aggh,
                                                short* __restrict__ aggl) {
  int wid = (int)((blockIdx.x * (size_t)blockDim.x + threadIdx.x) >> 6);
  int lane = threadIdx.x & 63;
  if (wid >= N_NODESC) return;
  int b = offs[wid], e = offs[wid + 1];
  const float4* hp = (const float4*)h;
  float4 acc = make_float4(0.f, 0.f, 0.f, 0.f);
  for (int k = b; k < e; ++k) {
    int s = csr[k];
    float w = onorm[s];
    float4 v = hp[(size_t)s * 64 + lane];
    acc.x = fmaf(v.x, w, acc.x);
    acc.y = fmaf(v.y, w, acc.y);
    acc.z = fmaf(v.z, w, acc.z);
    acc.w = fmaf(v.w, w, acc.w);
  }
  float wi = inorm[wid];
  float v[4] = {acc.x * wi, acc.y * wi, acc.z * wi, acc.w * wi};
  unsigned hb[4], lb[4];
#pragma unroll
  for (int j = 0; j < 4; ++j) {
    hb[j] = bf16rne(v[j]);
    float res = v[j] - __uint_as_float(hb[j]);
    lb[j] = bf16rne(res);
  }
  uint2 ph = make_uint2((hb[0] >> 16) | hb[1], (hb[2] >> 16) | hb[3]);
  uint2 pl = make_uint2((lb[0] >> 16) | lb[1], (lb[2] >> 16) | lb[3]);
  ((uint2*)aggh)[(size_t)wid * 64 + lane] = ph;
  ((uint2*)aggl)[(size_t)wid * 64 + lane] = pl;
}

// ---------------- W transpose + bf16 split: Wt[n][k] ----------------

__global__ __launch_bounds__(256) void k_wsplit(const float* __restrict__ W,
                                                short* __restrict__ Wth,
                                                short* __restrict__ Wtl) {
  int i = blockIdx.x * blockDim.x + threadIdx.x;  // i = k*256 + n
  if (i >= HID * HID) return;
  int k = i >> 8, n = i & 255;
  float v = W[i];
  unsigned hb = bf16rne(v);
  float res = v - __uint_as_float(hb);
  unsigned lb = bf16rne(res);
  Wth[(size_t)n * HID + k] = (short)(hb >> 16);
  Wtl[(size_t)n * HID + k] = (short)(lb >> 16);
}

// ---------------- MFMA GEMM: C[M x 256] = A @ W + bias, split-bf16 x3 ----------------
// Block = 256 thr = 4 waves; each wave owns 32 rows x 256 cols.
// ALL loops over acc indices are FULLY unrolled (rule #20: any runtime index
// into the f32x4 acc array sends it to scratch -> 1 GB of spill traffic, the
// round-3 regression).
// Fragment layouts (gfx950, HW-verified by round-3 absmax parity with fp32):
//   A: lane l holds A[l&15][8*(l>>4)+e], e=0..7 contiguous  (b128 load)
//   B: lane l holds B[8*(l>>4)+e][l&15]  -> from Wt[n][k] row-contiguous
//   C/D: col = lane&15, row = (lane>>4)*4 + reg

__global__ __launch_bounds__(256) void k_gemm_mfma(
    const short* __restrict__ Ah, const short* __restrict__ Al,
    const short* __restrict__ Wth, const short* __restrict__ Wtl,
    const float* __restrict__ bias, float* __restrict__ C, int M) {
  int t = threadIdx.x;
  int wave = t >> 6, lane = t & 63;
  int m0 = blockIdx.x * 128 + wave * 32;
  int lr = lane & 15;
  int lk = (lane >> 4) * 8;

  f32x4 acc[2][16];
#pragma unroll
  for (int mf = 0; mf < 2; ++mf)
#pragma unroll
    for (int nf = 0; nf < 16; ++nf) acc[mf][nf] = (f32x4){0.f, 0.f, 0.f, 0.f};

  int row0 = min(m0 + lr, M - 1);       // clamp: loads safe, writes guarded below
  int row1 = min(m0 + 16 + lr, M - 1);
  const short8v* a0h = (const short8v*)(Ah + (size_t)row0 * HID + lk);
  const short8v* a0l = (const short8v*)(Al + (size_t)row0 * HID + lk);
  const short8v* a1h = (const short8v*)(Ah + (size_t)row1 * HID + lk);
  const short8v* a1l = (const short8v*)(Al + (size_t)row1 * HID + lk);
  const short8v* wth = (const short8v*)(Wth + (size_t)lr * HID + lk);
  const short8v* wtl = (const short8v*)(Wtl + (size_t)lr * HID + lk);

  for (int k0 = 0; k0 < 8; ++k0) {  // K step = 32 shorts = 4 short8v
    short8v ah0 = a0h[k0 * 4];
    short8v al0 = a0l[k0 * 4];
    short8v ah1 = a1h[k0 * 4];
    short8v al1 = a1l[k0 * 4];
#pragma unroll
    for (int nf = 0; nf < 16; ++nf) {
      short8v wh = wth[(size_t)nf * 16 * (HID / 8) + k0 * 4];
      short8v wl = wtl[(size_t)nf * 16 * (HID / 8) + k0 * 4];
      acc[0][nf] = __builtin_amdgcn_mfma_f32_16x16x32_bf16(ah0, wh, acc[0][nf], 0, 0, 0);
      acc[0][nf] = __builtin_amdgcn_mfma_f32_16x16x32_bf16(al0, wh, acc[0][nf], 0, 0, 0);
      acc[0][nf] = __builtin_amdgcn_mfma_f32_16x16x32_bf16(ah0, wl, acc[0][nf], 0, 0, 0);
      acc[1][nf] = __builtin_amdgcn_mfma_f32_16x16x32_bf16(ah1, wh, acc[1][nf], 0, 0, 0);
      acc[1][nf] = __builtin_amdgcn_mfma_f32_16x16x32_bf16(al1, wh, acc[1][nf], 0, 0, 0);
      acc[1][nf] = __builtin_amdgcn_mfma_f32_16x16x32_bf16(ah1, wl, acc[1][nf], 0, 0, 0);
    }
  }

  int cr = (lane >> 4) * 4;
#pragma unroll
  for (int mf = 0; mf < 2; ++mf) {
#pragma unroll
    for (int nf = 0; nf < 16; ++nf) {
      float bv = bias[nf * 16 + lr];
      f32x4 v = acc[mf][nf];
#pragma unroll
      for (int r = 0; r < 4; ++r) {
        int row = m0 + mf * 16 + cr + r;
        if (row < M) C[(size_t)row * HID + nf * 16 + lr] = v[r] + bv;
      }
    }
  }
}

// ---------------- readout: sigmoid-weighted sum + segment max ----------------

__device__ __forceinline__ unsigned fkey(float f) {
  unsigned u = __float_as_uint(f);
  return (u & 0x80000000u) ? ~u : (u | 0x80000000u);
}

__device__ __forceinline__ void flush_group(int g, int lane, const float4& s,
                                            const uint4& mk, float* __restrict__ out,
                                            unsigned* __restrict__ mkeys) {
  float* hp = out + (size_t)g * 512 + (lane << 2);
  atomicAdd(hp + 0, s.x);
  atomicAdd(hp + 1, s.y);
  atomicAdd(hp + 2, s.z);
  atomicAdd(hp + 3, s.w);
  unsigned* mp = mkeys + ((size_t)g << 8) + (lane << 2);
  atomicMax(mp + 0, mk.x);
  atomicMax(mp + 1, mk.y);
  atomicMax(mp + 2, mk.z);
  atomicMax(mp + 3, mk.w);
}

__global__ __launch_bounds__(256) void k_readout(const float* __restrict__ h,
                                                 const int* __restrict__ gids,
                                                 const float* __restrict__ w_atom,
                                                 const float* __restrict__ b_atom,
                                                 float* __restrict__ out,
                                                 unsigned* __restrict__ mkeys) {
  int wid = (int)((blockIdx.x * (size_t)blockDim.x + threadIdx.x) >> 6);
  int lane = threadIdx.x & 63;
  int n0 = wid * RCHUNK;
  if (n0 >= N_NODESC) return;
  int n1 = min(n0 + RCHUNK, N_NODESC);
  float4 wa = ((const float4*)w_atom)[lane];
  float ba = b_atom[0];
  float4 s = make_float4(0.f, 0.f, 0.f, 0.f);
  uint4 mk = make_uint4(0u, 0u, 0u, 0u);
  int cur = gids[n0];
  for (int i = n0; i < n1; ++i) {
    int g = gids[i];
    if (g != cur) {
      flush_group(cur, lane, s, mk, out, mkeys);
      s = make_float4(0.f, 0.f, 0.f, 0.f);
      mk = make_uint4(0u, 0u, 0u, 0u);
      cur = g;
    }
    float4 v = ((const float4*)h)[(size_t)i * 64 + lane];
    float d = fmaf(v.x, wa.x, fmaf(v.y, wa.y, fmaf(v.z, wa.z, v.w * wa.w)));
#pragma unroll
    for (int o = 32; o > 0; o >>= 1) d += __shfl_xor(d, o, 64);
    float wgt = 1.0f / (1.0f + expf(-(d + ba)));
    s.x = fmaf(v.x, wgt, s.x);
    s.y = fmaf(v.y, wgt, s.y);
    s.z = fmaf(v.z, wgt, s.z);
    s.w = fmaf(v.w, wgt, s.w);
    mk.x = max(mk.x, fkey(v.x));
    mk.y = max(mk.y, fkey(v.y));
    mk.z = max(mk.z, fkey(v.z));
    mk.w = max(mk.w, fkey(v.w));
  }
  flush_group(cur, lane, s, mk, out, mkeys);
}

__global__ __launch_bounds__(256) void k_finalize(const unsigned* __restrict__ mkeys,
                                                  float* __restrict__ out) {
  int i = blockIdx.x * blockDim.x + threadIdx.x;
  if (i >= N_GRAPHSC * HID) return;
  int g = i >> 8, c = i & 255;
  unsigned k = mkeys[i];
  float f = 0.0f;
  if (k != 0u) f = (k & 0x80000000u) ? __uint_as_float(k ^ 0x80000000u) : __uint_as_float(~k);
  out[(size_t)g * 512 + 256 + c] = f;
}

// ---------------- predictor MLP ----------------

__global__ __launch_bounds__(256) void k_pred(const float* __restrict__ hg,
                                              const float* __restrict__ P1,
                                              const float* __restrict__ pb1,
                                              const float* __restrict__ P2,
                                              const float* __restrict__ pb2,
                                              float* __restrict__ pred) {
  __shared__ float P1s[32 * 256];
  __shared__ float hgt[32 * 16];
  int t = threadIdx.x;
  int g0 = blockIdx.x * 16;
  int tx = t & 63;
  int tg = t >> 6;
  float acc[4][4];
#pragma unroll
  for (int a = 0; a < 4; ++a)
#pragma unroll
    for (int b = 0; b < 4; ++b) acc[a][b] = 0.f;

  for (int kc = 0; kc < 512; kc += 32) {
    const float4* srcp = (const float4*)(P1 + (size_t)kc * 256);
    float4* dstp = (float4*)P1s;
    for (int i = t; i < 2048; i += 256) dstp[i] = srcp[i];
    {
      int g = t & 15, kk = t >> 4;
      const float* hrow = hg + (size_t)(g0 + g) * 512 + kc;
#pragma unroll
      for (int j = 0; j < 2; ++j) hgt[(kk * 2 + j) * 16 + g] = hrow[kk * 2 + j];
    }
    __syncthreads();
#pragma unroll 8
    for (int k = 0; k < 32; ++k) {
      float4 pv = *(const float4*)&P1s[k * 256 + (tx << 2)];
      float4 hv = *(const float4*)&hgt[(k << 4) + (tg << 2)];
      acc[0][0] = fmaf(hv.x, pv.x, acc[0][0]);
      acc[0][1] = fmaf(hv.x, pv.y, acc[0][1]);
      acc[0][2] = fmaf(hv.x, pv.z, acc[0][2]);
      acc[0][3] = fmaf(hv.x, pv.w, acc[0][3]);
      acc[1][0] = fmaf(hv.y, pv.x, acc[1][0]);
      acc[1][1] = fmaf(hv.y, pv.y, acc[1][1]);
      acc[1][2] = fmaf(hv.y, pv.z, acc[1][2]);
      acc[1][3] = fmaf(hv.y, pv.w, acc[1][3]);
      acc[2][0] = fmaf(hv.z, pv.x, acc[2][0]);
      acc[2][1] = fmaf(hv.z, pv.y, acc[2][1]);
      acc[2][2] = fmaf(hv.z, pv.z, acc[2][2]);
      acc[2][3] = fmaf(hv.z, pv.w, acc[2][3]);
      acc[3][0] = fmaf(hv.w, pv.x, acc[3][0]);
      acc[3][1] = fmaf(hv.w, pv.y, acc[3][1]);
      acc[3][2] = fmaf(hv.w, pv.z, acc[3][2]);
      acc[3][3] = fmaf(hv.w, pv.w, acc[3][3]);
    }
    __syncthreads();
  }

  float4 b1v = *(const float4*)(pb1 + (tx << 2));
  float4 p2v = *(const float4*)(P2 + (tx << 2));
  float pb2v = pb2[0];
#pragma unroll
  for (int g = 0; g < 4; ++g) {
    float r = fmaxf(acc[g][0] + b1v.x, 0.f) * p2v.x +
              fmaxf(acc[g][1] + b1v.y, 0.f) * p2v.y +
              fmaxf(acc[g][2] + b1v.z, 0.f) * p2v.z +
              fmaxf(acc[g][3] + b1v.w, 0.f) * p2v.w;
#pragma unroll
    for (int o = 32; o > 0; o >>= 1) r += __shfl_xor(r, o, 64);
    if (tx == 0) pred[g0 + (tg << 2) + g] = r + pb2v;
  }
}

// ---------------- host orchestration ----------------

extern "C" void kernel_launch(void* const* d_in, const int* in_sizes, int n_in,
                              void* d_out, int out_size, void* d_ws, size_t ws_size,
                              hipStream_t stream) {
  const float* feats = (const float*)d_in[0];
  const int* src = (const int*)d_in[1];
  const int* dst = (const int*)d_in[2];
  const int* gids = (const int*)d_in[3];
  const float* W1 = (const float*)d_in[4];
  const float* b1 = (const float*)d_in[5];
  const float* W2 = (const float*)d_in[6];
  const float* b2 = (const float*)d_in[7];
  const float* W3 = (const float*)d_in[8];
  const float* b3 = (const float*)d_in[9];
  const float* w_atom = (const float*)d_in[10];
  const float* b_atom = (const float*)d_in[11];
  const float* P1 = (const float*)d_in[12];
  const float* pb1 = (const float*)d_in[13];
  const float* P2 = (const float*)d_in[14];
  const float* pb2 = (const float*)d_in[15];
  float* out = (float*)d_out;

  char* base = (char*)d_ws;
  size_t off = 0;
  auto alloc = [&](size_t bytes) -> void* {
    void* p = base + off;
    off = (off + bytes + 511) & ~(size_t)511;
    return p;
  };
  int* outd = (int*)alloc((size_t)N_NODESC * 4);
  int* ind = (int*)alloc((size_t)N_NODESC * 4);
  float* onorm = (float*)alloc((size_t)N_NODESC * 4);
  float* inorm = (float*)alloc((size_t)N_NODESC * 4);
  int* offs = (int*)alloc((size_t)(N_NODESC + 1) * 4);
  int* cursor = (int*)alloc((size_t)N_NODESC * 4);
  int* csr = (int*)alloc((size_t)N_EDGESC * 4);
  float* agg1 = (float*)alloc((size_t)N_NODESC * IN_F * 4);
  float* bufA = (float*)alloc((size_t)N_NODESC * HID * 4);
  short* aggh = (short*)alloc((size_t)N_NODESC * HID * 2);
  short* aggl = (short*)alloc((size_t)N_NODESC * HID * 2);
  short* Wth2 = (short*)alloc((size_t)HID * HID * 2);
  short* Wtl2 = (short*)alloc((size_t)HID * HID * 2);
  short* Wth3 = (short*)alloc((size_t)HID * HID * 2);
  short* Wtl3 = (short*)alloc((size_t)HID * HID * 2);
  unsigned* mkeys = (unsigned*)alloc((size_t)N_GRAPHSC * HID * 4);

  hipMemsetAsync(outd, 0, (size_t)N_NODESC * 4, stream);
  hipMemsetAsync(ind, 0, (size_t)N_NODESC * 4, stream);
  hipMemsetAsync(cursor, 0, (size_t)N_NODESC * 4, stream);
  hipMemsetAsync(mkeys, 0, (size_t)N_GRAPHSC * HID * 4, stream);
  hipMemsetAsync(out, 0, (size_t)out_size * 4, stream);

  k_degrees<<<(N_EDGESC + 255) / 256, 256, 0, stream>>>(src, dst, outd, ind);
  k_norms<<<(N_NODESC + 255) / 256, 256, 0, stream>>>(outd, ind, onorm, inorm);
  k_scan<<<1, 1024, 0, stream>>>(ind, offs);
  k_fill<<<(N_EDGESC + 255) / 256, 256, 0, stream>>>(src, dst, offs, cursor, csr);

  // W splits (independent of graph pipeline)
  k_wsplit<<<(HID * HID + 255) / 256, 256, 0, stream>>>(W2, Wth2, Wtl2);
  k_wsplit<<<(HID * HID + 255) / 256, 256, 0, stream>>>(W3, Wth3, Wtl3);

  // layer 1
  k_agg16<<<(N_NODESC * IN_F + 255) / 256, 256, 0, stream>>>(feats, offs, csr, onorm,
                                                             inorm, agg1);
  k_mm16<<<2048, 256, 0, stream>>>(agg1, W1, b1, bufA);

  // layer 2
  k_agg256<<<(N_NODESC * 64 + 255) / 256, 256, 0, stream>>>(bufA, offs, csr, onorm,
                                                            inorm, aggh, aggl);
  k_gemm_mfma<<<(N_NODESC + 127) / 128, 256, 0, stream>>>(aggh, aggl, Wth2, Wtl2, b2,
                                                          bufA, N_NODESC);
  // layer 3
  k_agg256<<<(N_NODESC * 64 + 255) / 256, 256, 0, stream>>>(bufA, offs, csr, onorm,
                                                            inorm, aggh, aggl);
  k_gemm_mfma<<<(N_NODESC + 127) / 128, 256, 0, stream>>>(aggh, aggl, Wth3, Wtl3, b3,
                                                          bufA, N_NODESC);

  // readout + predictor
  int rwaves = (N_NODESC + RCHUNK - 1) / RCHUNK;
  k_readout<<<(rwaves * 64 + 255) / 256, 256, 0, stream>>>(bufA, gids, w_atom, b_atom,
                                                           out, mkeys);
  k_finalize<<<(N_GRAPHSC * HID + 255) / 256, 256, 0, stream>>>(mkeys, out);
  k_pred<<<N_GRAPHSC / 16, 256, 0, stream>>>(out, P1, pb1, P2, pb2,
                                             out + (size_t)N_GRAPHSC * 512);
}

// Round 10
// 880.246 us; speedup vs baseline: 1.7718x; 1.1206x over previous
//
#include <hip/hip_runtime.h>

#define N_NODESC 100000
#define N_EDGESC 300000
#define N_GRAPHSC 4000
#define IN_F 16
#define HID 256
#define RCHUNK 32

typedef __attribute__((ext_vector_type(8))) short short8v;   // 8 bf16 (4 VGPRs)
typedef __attribute__((ext_vector_type(4))) float f32x4;     // 4 fp32

// bf16 round-to-nearest-even, returned as fp32-aligned high bits
__device__ __forceinline__ unsigned bf16rne(float v) {
  unsigned u = __float_as_uint(v);
  return (u + 0x7fffu + ((u >> 16) & 1u)) & 0xffff0000u;
}

// ---------------- degree / norm / CSR build ----------------

__global__ __launch_bounds__(256) void k_degrees(const int* __restrict__ src,
                                                 const int* __restrict__ dst,
                                                 int* __restrict__ outd,
                                                 int* __restrict__ ind) {
  int e = blockIdx.x * blockDim.x + threadIdx.x;
  if (e < N_EDGESC) {
    atomicAdd(&outd[src[e]], 1);
    atomicAdd(&ind[dst[e]], 1);
  }
}

__global__ __launch_bounds__(256) void k_norms(const int* __restrict__ outd,
                                               const int* __restrict__ ind,
                                               float* __restrict__ onorm,
                                               float* __restrict__ inorm) {
  int i = blockIdx.x * blockDim.x + threadIdx.x;
  if (i < N_NODESC) {
    onorm[i] = rsqrtf((float)max(outd[i], 1));
    inorm[i] = rsqrtf((float)max(ind[i], 1));
  }
}

// single-block exclusive scan of in-degrees -> CSR offsets
__global__ __launch_bounds__(1024) void k_scan(const int* __restrict__ ind,
                                               int* __restrict__ offs) {
  __shared__ int sh[1024];
  const int n = N_NODESC;
  int t = threadIdx.x;
  int chunk = (n + 1023) >> 10;
  int b = t * chunk;
  int e = min(b + chunk, n);
  int s = 0;
  for (int i = b; i < e; ++i) s += ind[i];
  sh[t] = s;
  __syncthreads();
  for (int o = 1; o < 1024; o <<= 1) {
    int x = (t >= o) ? sh[t - o] : 0;
    __syncthreads();
    sh[t] += x;
    __syncthreads();
  }
  int pre = sh[t] - s;
  for (int i = b; i < e; ++i) {
    offs[i] = pre;
    pre += ind[i];
  }
  if (t == 1023) offs[n] = sh[1023];
}

__global__ __launch_bounds__(256) void k_fill(const int* __restrict__ src,
                                              const int* __restrict__ dst,
                                              const int* __restrict__ offs,
                                              int* __restrict__ cursor,
                                              int* __restrict__ csr) {
  int e = blockIdx.x * blockDim.x + threadIdx.x;
  if (e < N_EDGESC) {
    int d = dst[e];
    int p = offs[d] + atomicAdd(&cursor[d], 1);
    csr[p] = src[e];
  }
}

// ---------------- layer 1: 16-d aggregation + 16x256 matmul ----------------

__global__ __launch_bounds__(256) void k_agg16(const float* __restrict__ feats,
                                               const int* __restrict__ offs,
                                               const int* __restrict__ csr,
                                               const float* __restrict__ onorm,
                                               const float* __restrict__ inorm,
                                               float* __restrict__ agg1) {
  int gid = blockIdx.x * blockDim.x + threadIdx.x;
  int node = gid >> 4;
  if (node >= N_NODESC) return;
  int f = gid & 15;
  int b = offs[node], e = offs[node + 1];
  float acc = 0.f;
  for (int k = b; k < e; ++k) {
    int s = csr[k];
    acc = fmaf(feats[s * IN_F + f], onorm[s], acc);
  }
  agg1[(size_t)node * IN_F + f] = acc * inorm[node];
}

__global__ __launch_bounds__(256) void k_mm16(const float* __restrict__ agg1,
                                              const float* __restrict__ W,
                                              const float* __restrict__ bias,
                                              float* __restrict__ out) {
  __shared__ float Ws[IN_F * HID];
  __shared__ float bs[HID];
  int t = threadIdx.x;
  for (int i = t; i < IN_F * HID; i += 256) Ws[i] = W[i];
  bs[t] = bias[t];
  __syncthreads();
  for (int node = blockIdx.x; node < N_NODESC; node += gridDim.x) {
    float a[IN_F];
#pragma unroll
    for (int k = 0; k < IN_F; ++k) a[k] = agg1[(size_t)node * IN_F + k];
    float acc = bs[t];
#pragma unroll
    for (int k = 0; k < IN_F; ++k) acc = fmaf(a[k], Ws[k * HID + t], acc);
    out[(size_t)node * HID + t] = acc;
  }
}

// ---------------- 256-d aggregation: one wave per node, bf16-split output ----------------

__global__ __launch_bounds__(256) void k_agg256(const float* __restrict__ h,
                                                const int* __restrict__ offs,
                                                const int* __restrict__ csr,
                                                const float* __restrict__ onorm,
                                                const float* __restrict__ inorm,
                                                short* __restrict__ aggh,
                                                short* __restrict__ aggl) {
  int wid = (int)((blockIdx.x * (size_t)blockDim.x + threadIdx.x) >> 6);
  int lane = threadIdx.x & 63;
  if (wid >= N_NODESC) return;
  int b = offs[wid], e = offs[wid + 1];
  const float4* hp = (const float4*)h;
  float4 acc = make_float4(0.f, 0.f, 0.f, 0.f);
  for (int k = b; k < e; ++k) {
    int s = csr[k];
    float w = onorm[s];
    float4 v = hp[(size_t)s * 64 + lane];
    acc.x = fmaf(v.x, w, acc.x);
    acc.y = fmaf(v.y, w, acc.y);
    acc.z = fmaf(v.z, w, acc.z);
    acc.w = fmaf(v.w, w, acc.w);
  }
  float wi = inorm[wid];
  float v[4] = {acc.x * wi, acc.y * wi, acc.z * wi, acc.w * wi};
  unsigned hb[4], lb[4];
#pragma unroll
  for (int j = 0; j < 4; ++j) {
    hb[j] = bf16rne(v[j]);
    float res = v[j] - __uint_as_float(hb[j]);
    lb[j] = bf16rne(res);
  }
  uint2 ph = make_uint2((hb[0] >> 16) | hb[1], (hb[2] >> 16) | hb[3]);
  uint2 pl = make_uint2((lb[0] >> 16) | lb[1], (lb[2] >> 16) | lb[3]);
  ((uint2*)aggh)[(size_t)wid * 64 + lane] = ph;
  ((uint2*)aggl)[(size_t)wid * 64 + lane] = pl;
}

// ---------------- W transpose + bf16 split: Wt[n][k] ----------------

__global__ __launch_bounds__(256) void k_wsplit(const float* __restrict__ W,
                                                short* __restrict__ Wth,
                                                short* __restrict__ Wtl) {
  int i = blockIdx.x * blockDim.x + threadIdx.x;  // i = k*256 + n
  if (i >= HID * HID) return;
  int k = i >> 8, n = i & 255;
  float v = W[i];
  unsigned hb = bf16rne(v);
  float res = v - __uint_as_float(hb);
  unsigned lb = bf16rne(res);
  Wth[(size_t)n * HID + k] = (short)(hb >> 16);
  Wtl[(size_t)n * HID + k] = (short)(lb >> 16);
}

// ---------------- MFMA GEMM: C[M x 256] = A @ W + bias, split-bf16 x3 ----------------
// Round-8 counters: 210us, VGPR=140, MfmaUtil 7%, Occ 9%, HBM 9% -> latency-bound;
// acc[2][16]=128 VGPRs left ~12 spare regs -> MLP of 2-3 loads. This round: N-split
// (grid.y=2, 128 cols/block), acc[2][8]=64 VGPRs -> deeper load pipelining + more
// resident waves. All acc indices remain compile-time constants (rule #20).
// Fragment layouts unchanged (HW-verified):
//   A: lane l holds A[l&15][8*(l>>4)+e]  (b128 load)
//   B: lane l holds B[8*(l>>4)+e][l&15]  <- Wt[n][k] row-contiguous
//   C/D: col = lane&15, row = (lane>>4)*4 + reg

__global__ __launch_bounds__(256) void k_gemm_mfma(
    const short* __restrict__ Ah, const short* __restrict__ Al,
    const short* __restrict__ Wth, const short* __restrict__ Wtl,
    const float* __restrict__ bias, float* __restrict__ C, int M) {
  int t = threadIdx.x;
  int wave = t >> 6, lane = t & 63;
  int m0 = blockIdx.x * 128 + wave * 32;
  int bn = blockIdx.y * 128;
  int lr = lane & 15;
  int lk = (lane >> 4) * 8;

  f32x4 acc[2][8];
#pragma unroll
  for (int mf = 0; mf < 2; ++mf)
#pragma unroll
    for (int nf = 0; nf < 8; ++nf) acc[mf][nf] = (f32x4){0.f, 0.f, 0.f, 0.f};

  int row0 = min(m0 + lr, M - 1);       // clamp: loads safe, writes guarded below
  int row1 = min(m0 + 16 + lr, M - 1);
  const short8v* a0h = (const short8v*)(Ah + (size_t)row0 * HID + lk);
  const short8v* a0l = (const short8v*)(Al + (size_t)row0 * HID + lk);
  const short8v* a1h = (const short8v*)(Ah + (size_t)row1 * HID + lk);
  const short8v* a1l = (const short8v*)(Al + (size_t)row1 * HID + lk);
  const short8v* wth = (const short8v*)(Wth + (size_t)(bn + lr) * HID + lk);
  const short8v* wtl = (const short8v*)(Wtl + (size_t)(bn + lr) * HID + lk);

  for (int k0 = 0; k0 < 8; ++k0) {  // K step = 32 shorts = 4 short8v
    short8v ah0 = a0h[k0 * 4];
    short8v al0 = a0l[k0 * 4];
    short8v ah1 = a1h[k0 * 4];
    short8v al1 = a1l[k0 * 4];
#pragma unroll
    for (int nf = 0; nf < 8; ++nf) {
      short8v wh = wth[(size_t)nf * 16 * (HID / 8) + k0 * 4];
      short8v wl = wtl[(size_t)nf * 16 * (HID / 8) + k0 * 4];
      acc[0][nf] = __builtin_amdgcn_mfma_f32_16x16x32_bf16(ah0, wh, acc[0][nf], 0, 0, 0);
      acc[0][nf] = __builtin_amdgcn_mfma_f32_16x16x32_bf16(al0, wh, acc[0][nf], 0, 0, 0);
      acc[0][nf] = __builtin_amdgcn_mfma_f32_16x16x32_bf16(ah0, wl, acc[0][nf], 0, 0, 0);
      acc[1][nf] = __builtin_amdgcn_mfma_f32_16x16x32_bf16(ah1, wh, acc[1][nf], 0, 0, 0);
      acc[1][nf] = __builtin_amdgcn_mfma_f32_16x16x32_bf16(al1, wh, acc[1][nf], 0, 0, 0);
      acc[1][nf] = __builtin_amdgcn_mfma_f32_16x16x32_bf16(ah1, wl, acc[1][nf], 0, 0, 0);
    }
  }

  int cr = (lane >> 4) * 4;
#pragma unroll
  for (int mf = 0; mf < 2; ++mf) {
#pragma unroll
    for (int nf = 0; nf < 8; ++nf) {
      float bv = bias[bn + nf * 16 + lr];
      f32x4 v = acc[mf][nf];
#pragma unroll
      for (int r = 0; r < 4; ++r) {
        int row = m0 + mf * 16 + cr + r;
        if (row < M) C[(size_t)row * HID + bn + nf * 16 + lr] = v[r] + bv;
      }
    }
  }
}

// ---------------- readout: sigmoid-weighted sum + segment max ----------------

__device__ __forceinline__ unsigned fkey(float f) {
  unsigned u = __float_as_uint(f);
  return (u & 0x80000000u) ? ~u : (u | 0x80000000u);
}

__device__ __forceinline__ void flush_group(int g, int lane, const float4& s,
                                            const uint4& mk, float* __restrict__ out,
                                            unsigned* __restrict__ mkeys) {
  float* hp = out + (size_t)g * 512 + (lane << 2);
  atomicAdd(hp + 0, s.x);
  atomicAdd(hp + 1, s.y);
  atomicAdd(hp + 2, s.z);
  atomicAdd(hp + 3, s.w);
  unsigned* mp = mkeys + ((size_t)g << 8) + (lane << 2);
  atomicMax(mp + 0, mk.x);
  atomicMax(mp + 1, mk.y);
  atomicMax(mp + 2, mk.z);
  atomicMax(mp + 3, mk.w);
}

__global__ __launch_bounds__(256) void k_readout(const float* __restrict__ h,
                                                 const int* __restrict__ gids,
                                                 const float* __restrict__ w_atom,
                                                 const float* __restrict__ b_atom,
                                                 float* __restrict__ out,
                                                 unsigned* __restrict__ mkeys) {
  int wid = (int)((blockIdx.x * (size_t)blockDim.x + threadIdx.x) >> 6);
  int lane = threadIdx.x & 63;
  int n0 = wid * RCHUNK;
  if (n0 >= N_NODESC) return;
  int n1 = min(n0 + RCHUNK, N_NODESC);
  float4 wa = ((const float4*)w_atom)[lane];
  float ba = b_atom[0];
  float4 s = make_float4(0.f, 0.f, 0.f, 0.f);
  uint4 mk = make_uint4(0u, 0u, 0u, 0u);
  int cur = gids[n0];
  for (int i = n0; i < n1; ++i) {
    int g = gids[i];
    if (g != cur) {
      flush_group(cur, lane, s, mk, out, mkeys);
      s = make_float4(0.f, 0.f, 0.f, 0.f);
      mk = make_uint4(0u, 0u, 0u, 0u);
      cur = g;
    }
    float4 v = ((const float4*)h)[(size_t)i * 64 + lane];
    float d = fmaf(v.x, wa.x, fmaf(v.y, wa.y, fmaf(v.z, wa.z, v.w * wa.w)));
#pragma unroll
    for (int o = 32; o > 0; o >>= 1) d += __shfl_xor(d, o, 64);
    float wgt = 1.0f / (1.0f + expf(-(d + ba)));
    s.x = fmaf(v.x, wgt, s.x);
    s.y = fmaf(v.y, wgt, s.y);
    s.z = fmaf(v.z, wgt, s.z);
    s.w = fmaf(v.w, wgt, s.w);
    mk.x = max(mk.x, fkey(v.x));
    mk.y = max(mk.y, fkey(v.y));
    mk.z = max(mk.z, fkey(v.z));
    mk.w = max(mk.w, fkey(v.w));
  }
  flush_group(cur, lane, s, mk, out, mkeys);
}

__global__ __launch_bounds__(256) void k_finalize(const unsigned* __restrict__ mkeys,
                                                  float* __restrict__ out) {
  int i = blockIdx.x * blockDim.x + threadIdx.x;
  if (i >= N_GRAPHSC * HID) return;
  int g = i >> 8, c = i & 255;
  unsigned k = mkeys[i];
  float f = 0.0f;
  if (k != 0u) f = (k & 0x80000000u) ? __uint_as_float(k ^ 0x80000000u) : __uint_as_float(~k);
  out[(size_t)g * 512 + 256 + c] = f;
}

// ---------------- predictor MLP ----------------

__global__ __launch_bounds__(256) void k_pred(const float* __restrict__ hg,
                                              const float* __restrict__ P1,
                                              const float* __restrict__ pb1,
                                              const float* __restrict__ P2,
                                              const float* __restrict__ pb2,
                                              float* __restrict__ pred) {
  __shared__ float P1s[32 * 256];
  __shared__ float hgt[32 * 16];
  int t = threadIdx.x;
  int g0 = blockIdx.x * 16;
  int tx = t & 63;
  int tg = t >> 6;
  float acc[4][4];
#pragma unroll
  for (int a = 0; a < 4; ++a)
#pragma unroll
    for (int b = 0; b < 4; ++b) acc[a][b] = 0.f;

  for (int kc = 0; kc < 512; kc += 32) {
    const float4* srcp = (const float4*)(P1 + (size_t)kc * 256);
    float4* dstp = (float4*)P1s;
    for (int i = t; i < 2048; i += 256) dstp[i] = srcp[i];
    {
      int g = t & 15, kk = t >> 4;
      const float* hrow = hg + (size_t)(g0 + g) * 512 + kc;
#pragma unroll
      for (int j = 0; j < 2; ++j) hgt[(kk * 2 + j) * 16 + g] = hrow[kk * 2 + j];
    }
    __syncthreads();
#pragma unroll 8
    for (int k = 0; k < 32; ++k) {
      float4 pv = *(const float4*)&P1s[k * 256 + (tx << 2)];
      float4 hv = *(const float4*)&hgt[(k << 4) + (tg << 2)];
      acc[0][0] = fmaf(hv.x, pv.x, acc[0][0]);
      acc[0][1] = fmaf(hv.x, pv.y, acc[0][1]);
      acc[0][2] = fmaf(hv.x, pv.z, acc[0][2]);
      acc[0][3] = fmaf(hv.x, pv.w, acc[0][3]);
      acc[1][0] = fmaf(hv.y, pv.x, acc[1][0]);
      acc[1][1] = fmaf(hv.y, pv.y, acc[1][1]);
      acc[1][2] = fmaf(hv.y, pv.z, acc[1][2]);
      acc[1][3] = fmaf(hv.y, pv.w, acc[1][3]);
      acc[2][0] = fmaf(hv.z, pv.x, acc[2][0]);
      acc[2][1] = fmaf(hv.z, pv.y, acc[2][1]);
      acc[2][2] = fmaf(hv.z, pv.z, acc[2][2]);
      acc[2][3] = fmaf(hv.z, pv.w, acc[2][3]);
      acc[3][0] = fmaf(hv.w, pv.x, acc[3][0]);
      acc[3][1] = fmaf(hv.w, pv.y, acc[3][1]);
      acc[3][2] = fmaf(hv.w, pv.z, acc[3][2]);
      acc[3][3] = fmaf(hv.w, pv.w, acc[3][3]);
    }
    __syncthreads();
  }

  float4 b1v = *(const float4*)(pb1 + (tx << 2));
  float4 p2v = *(const float4*)(P2 + (tx << 2));
  float pb2v = pb2[0];
#pragma unroll
  for (int g = 0; g < 4; ++g) {
    float r = fmaxf(acc[g][0] + b1v.x, 0.f) * p2v.x +
              fmaxf(acc[g][1] + b1v.y, 0.f) * p2v.y +
              fmaxf(acc[g][2] + b1v.z, 0.f) * p2v.z +
              fmaxf(acc[g][3] + b1v.w, 0.f) * p2v.w;
#pragma unroll
    for (int o = 32; o > 0; o >>= 1) r += __shfl_xor(r, o, 64);
    if (tx == 0) pred[g0 + (tg << 2) + g] = r + pb2v;
  }
}

// ---------------- host orchestration ----------------

extern "C" void kernel_launch(void* const* d_in, const int* in_sizes, int n_in,
                              void* d_out, int out_size, void* d_ws, size_t ws_size,
                              hipStream_t stream) {
  const float* feats = (const float*)d_in[0];
  const int* src = (const int*)d_in[1];
  const int* dst = (const int*)d_in[2];
  const int* gids = (const int*)d_in[3];
  const float* W1 = (const float*)d_in[4];
  const float* b1 = (const float*)d_in[5];
  const float* W2 = (const float*)d_in[6];
  const float* b2 = (const float*)d_in[7];
  const float* W3 = (const float*)d_in[8];
  const float* b3 = (const float*)d_in[9];
  const float* w_atom = (const float*)d_in[10];
  const float* b_atom = (const float*)d_in[11];
  const float* P1 = (const float*)d_in[12];
  const float* pb1 = (const float*)d_in[13];
  const float* P2 = (const float*)d_in[14];
  const float* pb2 = (const float*)d_in[15];
  float* out = (float*)d_out;

  char* base = (char*)d_ws;
  size_t off = 0;
  auto alloc = [&](size_t bytes) -> void* {
    void* p = base + off;
    off = (off + bytes + 511) & ~(size_t)511;
    return p;
  };
  int* outd = (int*)alloc((size_t)N_NODESC * 4);
  int* ind = (int*)alloc((size_t)N_NODESC * 4);
  float* onorm = (float*)alloc((size_t)N_NODESC * 4);
  float* inorm = (float*)alloc((size_t)N_NODESC * 4);
  int* offs = (int*)alloc((size_t)(N_NODESC + 1) * 4);
  int* cursor = (int*)alloc((size_t)N_NODESC * 4);
  int* csr = (int*)alloc((size_t)N_EDGESC * 4);
  float* agg1 = (float*)alloc((size_t)N_NODESC * IN_F * 4);
  float* bufA = (float*)alloc((size_t)N_NODESC * HID * 4);
  short* aggh = (short*)alloc((size_t)N_NODESC * HID * 2);
  short* aggl = (short*)alloc((size_t)N_NODESC * HID * 2);
  short* Wth2 = (short*)alloc((size_t)HID * HID * 2);
  short* Wtl2 = (short*)alloc((size_t)HID * HID * 2);
  short* Wth3 = (short*)alloc((size_t)HID * HID * 2);
  short* Wtl3 = (short*)alloc((size_t)HID * HID * 2);
  unsigned* mkeys = (unsigned*)alloc((size_t)N_GRAPHSC * HID * 4);

  hipMemsetAsync(outd, 0, (size_t)N_NODESC * 4, stream);
  hipMemsetAsync(ind, 0, (size_t)N_NODESC * 4, stream);
  hipMemsetAsync(cursor, 0, (size_t)N_NODESC * 4, stream);
  hipMemsetAsync(mkeys, 0, (size_t)N_GRAPHSC * HID * 4, stream);
  hipMemsetAsync(out, 0, (size_t)out_size * 4, stream);

  k_degrees<<<(N_EDGESC + 255) / 256, 256, 0, stream>>>(src, dst, outd, ind);
  k_norms<<<(N_NODESC + 255) / 256, 256, 0, stream>>>(outd, ind, onorm, inorm);
  k_scan<<<1, 1024, 0, stream>>>(ind, offs);
  k_fill<<<(N_EDGESC + 255) / 256, 256, 0, stream>>>(src, dst, offs, cursor, csr);

  // W splits (independent of graph pipeline)
  k_wsplit<<<(HID * HID + 255) / 256, 256, 0, stream>>>(W2, Wth2, Wtl2);
  k_wsplit<<<(HID * HID + 255) / 256, 256, 0, stream>>>(W3, Wth3, Wtl3);

  // layer 1
  k_agg16<<<(N_NODESC * IN_F + 255) / 256, 256, 0, stream>>>(feats, offs, csr, onorm,
                                                             inorm, agg1);
  k_mm16<<<2048, 256, 0, stream>>>(agg1, W1, b1, bufA);

  // layer 2
  k_agg256<<<(N_NODESC * 64 + 255) / 256, 256, 0, stream>>>(bufA, offs, csr, onorm,
                                                            inorm, aggh, aggl);
  k_gemm_mfma<<<dim3((N_NODESC + 127) / 128, 2), 256, 0, stream>>>(aggh, aggl, Wth2,
                                                                   Wtl2, b2, bufA,
                                                                   N_NODESC);
  // layer 3
  k_agg256<<<(N_NODESC * 64 + 255) / 256, 256, 0, stream>>>(bufA, offs, csr, onorm,
                                                            inorm, aggh, aggl);
  k_gemm_mfma<<<dim3((N_NODESC + 127) / 128, 2), 256, 0, stream>>>(aggh, aggl, Wth3,
                                                                   Wtl3, b3, bufA,
                                                                   N_NODESC);

  // readout + predictor
  int rwaves = (N_NODESC + RCHUNK - 1) / RCHUNK;
  k_readout<<<(rwaves * 64 + 255) / 256, 256, 0, stream>>>(bufA, gids, w_atom, b_atom,
                                                           out, mkeys);
  k_finalize<<<(N_GRAPHSC * HID + 255) / 256, 256, 0, stream>>>(mkeys, out);
  k_pred<<<N_GRAPHSC / 16, 256, 0, stream>>>(out, P1, pb1, P2, pb2,
                                             out + (size_t)N_GRAPHSC * 512);
}

// Round 12
// 738.566 us; speedup vs baseline: 2.1116x; 1.1918x over previous
//
#include <hip/hip_runtime.h>

#define N_NODESC 100000
#define N_EDGESC 300000
#define N_GRAPHSC 4000
#define IN_F 16
#define HID 256
#define RCHUNK 32

typedef __attribute__((ext_vector_type(8))) short short8v;   // 8 bf16 (4 VGPRs)
typedef __attribute__((ext_vector_type(4))) float f32x4;     // 4 fp32

// bf16 round-to-nearest-even, returned as fp32-aligned high bits
__device__ __forceinline__ unsigned bf16rne(float v) {
  unsigned u = __float_as_uint(v);
  return (u + 0x7fffu + ((u >> 16) & 1u)) & 0xffff0000u;
}

// ---------------- degree / norm / CSR build ----------------

__global__ __launch_bounds__(256) void k_degrees(const int* __restrict__ src,
                                                 const int* __restrict__ dst,
                                                 int* __restrict__ outd,
                                                 int* __restrict__ ind) {
  int e = blockIdx.x * blockDim.x + threadIdx.x;
  if (e < N_EDGESC) {
    atomicAdd(&outd[src[e]], 1);
    atomicAdd(&ind[dst[e]], 1);
  }
}

__global__ __launch_bounds__(256) void k_norms(const int* __restrict__ outd,
                                               const int* __restrict__ ind,
                                               float* __restrict__ onorm,
                                               float* __restrict__ inorm) {
  int i = blockIdx.x * blockDim.x + threadIdx.x;
  if (i < N_NODESC) {
    onorm[i] = rsqrtf((float)max(outd[i], 1));
    inorm[i] = rsqrtf((float)max(ind[i], 1));
  }
}

// Parallel CSR offset assignment. Replaces the 1-block serial scan (round-10
// profile: 5x k_scan @161us, Occupancy 0.16% -- 18% of runtime on one CU).
// Regions need only be DISJOINT, not ordered: block-local LDS scan + one
// atomicAdd per block for the base. Consumers use offs[i] + ind[i] as the end.
__global__ __launch_bounds__(256) void k_offs(const int* __restrict__ ind,
                                              int* __restrict__ offs,
                                              int* __restrict__ total) {
  __shared__ int sh[256];
  __shared__ int base;
  int t = threadIdx.x;
  int i = blockIdx.x * 256 + t;
  int v = (i < N_NODESC) ? ind[i] : 0;
  sh[t] = v;
  __syncthreads();
  for (int o = 1; o < 256; o <<= 1) {
    int x = (t >= o) ? sh[t - o] : 0;
    __syncthreads();
    sh[t] += x;
    __syncthreads();
  }
  if (t == 255) base = atomicAdd(total, sh[255]);
  __syncthreads();
  if (i < N_NODESC) offs[i] = base + sh[t] - v;  // exclusive local prefix + base
}

__global__ __launch_bounds__(256) void k_fill(const int* __restrict__ src,
                                              const int* __restrict__ dst,
                                              const int* __restrict__ offs,
                                              int* __restrict__ cursor,
                                              int* __restrict__ csr) {
  int e = blockIdx.x * blockDim.x + threadIdx.x;
  if (e < N_EDGESC) {
    int d = dst[e];
    int p = offs[d] + atomicAdd(&cursor[d], 1);
    csr[p] = src[e];
  }
}

// ---------------- layer 1: 16-d aggregation + 16x256 matmul ----------------

__global__ __launch_bounds__(256) void k_agg16(const float* __restrict__ feats,
                                               const int* __restrict__ offs,
                                               const int* __restrict__ ind,
                                               const int* __restrict__ csr,
                                               const float* __restrict__ onorm,
                                               const float* __restrict__ inorm,
                                               float* __restrict__ agg1) {
  int gid = blockIdx.x * blockDim.x + threadIdx.x;
  int node = gid >> 4;
  if (node >= N_NODESC) return;
  int f = gid & 15;
  int b = offs[node], e = b + ind[node];
  float acc = 0.f;
  for (int k = b; k < e; ++k) {
    int s = csr[k];
    acc = fmaf(feats[s * IN_F + f], onorm[s], acc);
  }
  agg1[(size_t)node * IN_F + f] = acc * inorm[node];
}

__global__ __launch_bounds__(256) void k_mm16(const float* __restrict__ agg1,
                                              const float* __restrict__ W,
                                              const float* __restrict__ bias,
                                              float* __restrict__ out) {
  __shared__ float Ws[IN_F * HID];
  __shared__ float bs[HID];
  int t = threadIdx.x;
  for (int i = t; i < IN_F * HID; i += 256) Ws[i] = W[i];
  bs[t] = bias[t];
  __syncthreads();
  for (int node = blockIdx.x; node < N_NODESC; node += gridDim.x) {
    float a[IN_F];
#pragma unroll
    for (int k = 0; k < IN_F; ++k) a[k] = agg1[(size_t)node * IN_F + k];
    float acc = bs[t];
#pragma unroll
    for (int k = 0; k < IN_F; ++k) acc = fmaf(a[k], Ws[k * HID + t], acc);
    out[(size_t)node * HID + t] = acc;
  }
}

// ---------------- 256-d aggregation: one wave per node, bf16-split output ----------------

__global__ __launch_bounds__(256) void k_agg256(const float* __restrict__ h,
                                                const int* __restrict__ offs,
                                                const int* __restrict__ ind,
                                                const int* __restrict__ csr,
                                                const float* __restrict__ onorm,
                                                const float* __restrict__ inorm,
                                                short* __restrict__ aggh,
                                                short* __restrict__ aggl) {
  int wid = (int)((blockIdx.x * (size_t)blockDim.x + threadIdx.x) >> 6);
  int lane = threadIdx.x & 63;
  if (wid >= N_NODESC) return;
  int b = offs[wid], e = b + ind[wid];
  const float4* hp = (const float4*)h;
  float4 acc = make_float4(0.f, 0.f, 0.f, 0.f);
  for (int k = b; k < e; ++k) {
    int s = csr[k];
    float w = onorm[s];
    float4 v = hp[(size_t)s * 64 + lane];
    acc.x = fmaf(v.x, w, acc.x);
    acc.y = fmaf(v.y, w, acc.y);
    acc.z = fmaf(v.z, w, acc.z);
    acc.w = fmaf(v.w, w, acc.w);
  }
  float wi = inorm[wid];
  float v[4] = {acc.x * wi, acc.y * wi, acc.z * wi, acc.w * wi};
  unsigned hb[4], lb[4];
#pragma unroll
  for (int j = 0; j < 4; ++j) {
    hb[j] = bf16rne(v[j]);
    float res = v[j] - __uint_as_float(hb[j]);
    lb[j] = bf16rne(res);
  }
  uint2 ph = make_uint2((hb[0] >> 16) | hb[1], (hb[2] >> 16) | hb[3]);
  uint2 pl = make_uint2((lb[0] >> 16) | lb[1], (lb[2] >> 16) | lb[3]);
  ((uint2*)aggh)[(size_t)wid * 64 + lane] = ph;
  ((uint2*)aggl)[(size_t)wid * 64 + lane] = pl;
}

// ---------------- W transpose + bf16 split: Wt[n][k] ----------------

__global__ __launch_bounds__(256) void k_wsplit(const float* __restrict__ W,
                                                short* __restrict__ Wth,
                                                short* __restrict__ Wtl) {
  int i = blockIdx.x * blockDim.x + threadIdx.x;  // i = k*256 + n
  if (i >= HID * HID) return;
  int k = i >> 8, n = i & 255;
  float v = W[i];
  unsigned hb = bf16rne(v);
  float res = v - __uint_as_float(hb);
  unsigned lb = bf16rne(res);
  Wth[(size_t)n * HID + k] = (short)(hb >> 16);
  Wtl[(size_t)n * HID + k] = (short)(lb >> 16);
}

// ---------------- MFMA GEMM: C[M x 256] = A @ W + bias, split-bf16 x3 ----------------
// N-split (grid.y=2, 128 cols/block), acc[2][8]=64 VGPRs; all acc indices
// compile-time (rule #20). Fragment layouts HW-verified (rounds 3/8/10).

__global__ __launch_bounds__(256) void k_gemm_mfma(
    const short* __restrict__ Ah, const short* __restrict__ Al,
    const short* __restrict__ Wth, const short* __restrict__ Wtl,
    const float* __restrict__ bias, float* __restrict__ C, int M) {
  int t = threadIdx.x;
  int wave = t >> 6, lane = t & 63;
  int m0 = blockIdx.x * 128 + wave * 32;
  int bn = blockIdx.y * 128;
  int lr = lane & 15;
  int lk = (lane >> 4) * 8;

  f32x4 acc[2][8];
#pragma unroll
  for (int mf = 0; mf < 2; ++mf)
#pragma unroll
    for (int nf = 0; nf < 8; ++nf) acc[mf][nf] = (f32x4){0.f, 0.f, 0.f, 0.f};

  int row0 = min(m0 + lr, M - 1);       // clamp: loads safe, writes guarded below
  int row1 = min(m0 + 16 + lr, M - 1);
  const short8v* a0h = (const short8v*)(Ah + (size_t)row0 * HID + lk);
  const short8v* a0l = (const short8v*)(Al + (size_t)row0 * HID + lk);
  const short8v* a1h = (const short8v*)(Ah + (size_t)row1 * HID + lk);
  const short8v* a1l = (const short8v*)(Al + (size_t)row1 * HID + lk);
  const short8v* wth = (const short8v*)(Wth + (size_t)(bn + lr) * HID + lk);
  const short8v* wtl = (const short8v*)(Wtl + (size_t)(bn + lr) * HID + lk);

  for (int k0 = 0; k0 < 8; ++k0) {  // K step = 32 shorts = 4 short8v
    short8v ah0 = a0h[k0 * 4];
    short8v al0 = a0l[k0 * 4];
    short8v ah1 = a1h[k0 * 4];
    short8v al1 = a1l[k0 * 4];
#pragma unroll
    for (int nf = 0; nf < 8; ++nf) {
      short8v wh = wth[(size_t)nf * 16 * (HID / 8) + k0 * 4];
      short8v wl = wtl[(size_t)nf * 16 * (HID / 8) + k0 * 4];
      acc[0][nf] = __builtin_amdgcn_mfma_f32_16x16x32_bf16(ah0, wh, acc[0][nf], 0, 0, 0);
      acc[0][nf] = __builtin_amdgcn_mfma_f32_16x16x32_bf16(al0, wh, acc[0][nf], 0, 0, 0);
      acc[0][nf] = __builtin_amdgcn_mfma_f32_16x16x32_bf16(ah0, wl, acc[0][nf], 0, 0, 0);
      acc[1][nf] = __builtin_amdgcn_mfma_f32_16x16x32_bf16(ah1, wh, acc[1][nf], 0, 0, 0);
      acc[1][nf] = __builtin_amdgcn_mfma_f32_16x16x32_bf16(al1, wh, acc[1][nf], 0, 0, 0);
      acc[1][nf] = __builtin_amdgcn_mfma_f32_16x16x32_bf16(ah1, wl, acc[1][nf], 0, 0, 0);
    }
  }

  int cr = (lane >> 4) * 4;
#pragma unroll
  for (int mf = 0; mf < 2; ++mf) {
#pragma unroll
    for (int nf = 0; nf < 8; ++nf) {
      float bv = bias[bn + nf * 16 + lr];
      f32x4 v = acc[mf][nf];
#pragma unroll
      for (int r = 0; r < 4; ++r) {
        int row = m0 + mf * 16 + cr + r;
        if (row < M) C[(size_t)row * HID + bn + nf * 16 + lr] = v[r] + bv;
      }
    }
  }
}

// ---------------- readout: sigmoid-weighted sum + segment max ----------------

__device__ __forceinline__ unsigned fkey(float f) {
  unsigned u = __float_as_uint(f);
  return (u & 0x80000000u) ? ~u : (u | 0x80000000u);
}

__device__ __forceinline__ void flush_group(int g, int lane, const float4& s,
                                            const uint4& mk, float* __restrict__ out,
                                            unsigned* __restrict__ mkeys) {
  float* hp = out + (size_t)g * 512 + (lane << 2);
  atomicAdd(hp + 0, s.x);
  atomicAdd(hp + 1, s.y);
  atomicAdd(hp + 2, s.z);
  atomicAdd(hp + 3, s.w);
  unsigned* mp = mkeys + ((size_t)g << 8) + (lane << 2);
  atomicMax(mp + 0, mk.x);
  atomicMax(mp + 1, mk.y);
  atomicMax(mp + 2, mk.z);
  atomicMax(mp + 3, mk.w);
}

__global__ __launch_bounds__(256) void k_readout(const float* __restrict__ h,
                                                 const int* __restrict__ gids,
                                                 const float* __restrict__ w_atom,
                                                 const float* __restrict__ b_atom,
                                                 float* __restrict__ out,
                                                 unsigned* __restrict__ mkeys) {
  int wid = (int)((blockIdx.x * (size_t)blockDim.x + threadIdx.x) >> 6);
  int lane = threadIdx.x & 63;
  int n0 = wid * RCHUNK;
  if (n0 >= N_NODESC) return;
  int n1 = min(n0 + RCHUNK, N_NODESC);
  float4 wa = ((const float4*)w_atom)[lane];
  float ba = b_atom[0];
  float4 s = make_float4(0.f, 0.f, 0.f, 0.f);
  uint4 mk = make_uint4(0u, 0u, 0u, 0u);
  int cur = gids[n0];
  for (int i = n0; i < n1; ++i) {
    int g = gids[i];
    if (g != cur) {
      flush_group(cur, lane, s, mk, out, mkeys);
      s = make_float4(0.f, 0.f, 0.f, 0.f);
      mk = make_uint4(0u, 0u, 0u, 0u);
      cur = g;
    }
    float4 v = ((const float4*)h)[(size_t)i * 64 + lane];
    float d = fmaf(v.x, wa.x, fmaf(v.y, wa.y, fmaf(v.z, wa.z, v.w * wa.w)));
#pragma unroll
    for (int o = 32; o > 0; o >>= 1) d += __shfl_xor(d, o, 64);
    float wgt = 1.0f / (1.0f + expf(-(d + ba)));
    s.x = fmaf(v.x, wgt, s.x);
    s.y = fmaf(v.y, wgt, s.y);
    s.z = fmaf(v.z, wgt, s.z);
    s.w = fmaf(v.w, wgt, s.w);
    mk.x = max(mk.x, fkey(v.x));
    mk.y = max(mk.y, fkey(v.y));
    mk.z = max(mk.z, fkey(v.z));
    mk.w = max(mk.w, fkey(v.w));
  }
  flush_group(cur, lane, s, mk, out, mkeys);
}

__global__ __launch_bounds__(256) void k_finalize(const unsigned* __restrict__ mkeys,
                                                  float* __restrict__ out) {
  int i = blockIdx.x * blockDim.x + threadIdx.x;
  if (i >= N_GRAPHSC * HID) return;
  int g = i >> 8, c = i & 255;
  unsigned k = mkeys[i];
  float f = 0.0f;
  if (k != 0u) f = (k & 0x80000000u) ? __uint_as_float(k ^ 0x80000000u) : __uint_as_float(~k);
  out[(size_t)g * 512 + 256 + c] = f;
}

// ---------------- predictor MLP ----------------

__global__ __launch_bounds__(256) void k_pred(const float* __restrict__ hg,
                                              const float* __restrict__ P1,
                                              const float* __restrict__ pb1,
                                              const float* __restrict__ P2,
                                              const float* __restrict__ pb2,
                                              float* __restrict__ pred) {
  __shared__ float P1s[32 * 256];
  __shared__ float hgt[32 * 16];
  int t = threadIdx.x;
  int g0 = blockIdx.x * 16;
  int tx = t & 63;
  int tg = t >> 6;
  float acc[4][4];
#pragma unroll
  for (int a = 0; a < 4; ++a)
#pragma unroll
    for (int b = 0; b < 4; ++b) acc[a][b] = 0.f;

  for (int kc = 0; kc < 512; kc += 32) {
    const float4* srcp = (const float4*)(P1 + (size_t)kc * 256);
    float4* dstp = (float4*)P1s;
    for (int i = t; i < 2048; i += 256) dstp[i] = srcp[i];
    {
      int g = t & 15, kk = t >> 4;
      const float* hrow = hg + (size_t)(g0 + g) * 512 + kc;
#pragma unroll
      for (int j = 0; j < 2; ++j) hgt[(kk * 2 + j) * 16 + g] = hrow[kk * 2 + j];
    }
    __syncthreads();
#pragma unroll 8
    for (int k = 0; k < 32; ++k) {
      float4 pv = *(const float4*)&P1s[k * 256 + (tx << 2)];
      float4 hv = *(const float4*)&hgt[(k << 4) + (tg << 2)];
      acc[0][0] = fmaf(hv.x, pv.x, acc[0][0]);
      acc[0][1] = fmaf(hv.x, pv.y, acc[0][1]);
      acc[0][2] = fmaf(hv.x, pv.z, acc[0][2]);
      acc[0][3] = fmaf(hv.x, pv.w, acc[0][3]);
      acc[1][0] = fmaf(hv.y, pv.x, acc[1][0]);
      acc[1][1] = fmaf(hv.y, pv.y, acc[1][1]);
      acc[1][2] = fmaf(hv.y, pv.z, acc[1][2]);
      acc[1][3] = fmaf(hv.y, pv.w, acc[1][3]);
      acc[2][0] = fmaf(hv.z, pv.x, acc[2][0]);
      acc[2][1] = fmaf(hv.z, pv.y, acc[2][1]);
      acc[2][2] = fmaf(hv.z, pv.z, acc[2][2]);
      acc[2][3] = fmaf(hv.z, pv.w, acc[2][3]);
      acc[3][0] = fmaf(hv.w, pv.x, acc[3][0]);
      acc[3][1] = fmaf(hv.w, pv.y, acc[3][1]);
      acc[3][2] = fmaf(hv.w, pv.z, acc[3][2]);
      acc[3][3] = fmaf(hv.w, pv.w, acc[3][3]);
    }
    __syncthreads();
  }

  float4 b1v = *(const float4*)(pb1 + (tx << 2));
  float4 p2v = *(const float4*)(P2 + (tx << 2));
  float pb2v = pb2[0];
#pragma unroll
  for (int g = 0; g < 4; ++g) {
    float r = fmaxf(acc[g][0] + b1v.x, 0.f) * p2v.x +
              fmaxf(acc[g][1] + b1v.y, 0.f) * p2v.y +
              fmaxf(acc[g][2] + b1v.z, 0.f) * p2v.z +
              fmaxf(acc[g][3] + b1v.w, 0.f) * p2v.w;
#pragma unroll
    for (int o = 32; o > 0; o >>= 1) r += __shfl_xor(r, o, 64);
    if (tx == 0) pred[g0 + (tg << 2) + g] = r + pb2v;
  }
}

// ---------------- host orchestration ----------------

extern "C" void kernel_launch(void* const* d_in, const int* in_sizes, int n_in,
                              void* d_out, int out_size, void* d_ws, size_t ws_size,
                              hipStream_t stream) {
  const float* feats = (const float*)d_in[0];
  const int* src = (const int*)d_in[1];
  const int* dst = (const int*)d_in[2];
  const int* gids = (const int*)d_in[3];
  const float* W1 = (const float*)d_in[4];
  const float* b1 = (const float*)d_in[5];
  const float* W2 = (const float*)d_in[6];
  const float* b2 = (const float*)d_in[7];
  const float* W3 = (const float*)d_in[8];
  const float* b3 = (const float*)d_in[9];
  const float* w_atom = (const float*)d_in[10];
  const float* b_atom = (const float*)d_in[11];
  const float* P1 = (const float*)d_in[12];
  const float* pb1 = (const float*)d_in[13];
  const float* P2 = (const float*)d_in[14];
  const float* pb2 = (const float*)d_in[15];
  float* out = (float*)d_out;

  char* base = (char*)d_ws;
  size_t off = 0;
  auto alloc = [&](size_t bytes) -> void* {
    void* p = base + off;
    off = (off + bytes + 511) & ~(size_t)511;
    return p;
  };
  int* outd = (int*)alloc((size_t)N_NODESC * 4);
  int* ind = (int*)alloc((size_t)N_NODESC * 4);
  float* onorm = (float*)alloc((size_t)N_NODESC * 4);
  float* inorm = (float*)alloc((size_t)N_NODESC * 4);
  int* offs = (int*)alloc((size_t)(N_NODESC + 1) * 4);
  int* cursor = (int*)alloc((size_t)N_NODESC * 4);
  int* total = (int*)alloc(4);
  int* csr = (int*)alloc((size_t)N_EDGESC * 4);
  float* agg1 = (float*)alloc((size_t)N_NODESC * IN_F * 4);
  float* bufA = (float*)alloc((size_t)N_NODESC * HID * 4);
  short* aggh = (short*)alloc((size_t)N_NODESC * HID * 2);
  short* aggl = (short*)alloc((size_t)N_NODESC * HID * 2);
  short* Wth2 = (short*)alloc((size_t)HID * HID * 2);
  short* Wtl2 = (short*)alloc((size_t)HID * HID * 2);
  short* Wth3 = (short*)alloc((size_t)HID * HID * 2);
  short* Wtl3 = (short*)alloc((size_t)HID * HID * 2);
  unsigned* mkeys = (unsigned*)alloc((size_t)N_GRAPHSC * HID * 4);

  hipMemsetAsync(outd, 0, (size_t)N_NODESC * 4, stream);
  hipMemsetAsync(ind, 0, (size_t)N_NODESC * 4, stream);
  hipMemsetAsync(cursor, 0, (size_t)N_NODESC * 4, stream);
  hipMemsetAsync(total, 0, 4, stream);
  hipMemsetAsync(mkeys, 0, (size_t)N_GRAPHSC * HID * 4, stream);
  hipMemsetAsync(out, 0, (size_t)out_size * 4, stream);

  k_degrees<<<(N_EDGESC + 255) / 256, 256, 0, stream>>>(src, dst, outd, ind);
  k_norms<<<(N_NODESC + 255) / 256, 256, 0, stream>>>(outd, ind, onorm, inorm);
  k_offs<<<(N_NODESC + 255) / 256, 256, 0, stream>>>(ind, offs, total);
  k_fill<<<(N_EDGESC + 255) / 256, 256, 0, stream>>>(src, dst, offs, cursor, csr);

  // W splits (independent of graph pipeline)
  k_wsplit<<<(HID * HID + 255) / 256, 256, 0, stream>>>(W2, Wth2, Wtl2);
  k_wsplit<<<(HID * HID + 255) / 256, 256, 0, stream>>>(W3, Wth3, Wtl3);

  // layer 1
  k_agg16<<<(N_NODESC * IN_F + 255) / 256, 256, 0, stream>>>(feats, offs, ind, csr,
                                                             onorm, inorm, agg1);
  k_mm16<<<2048, 256, 0, stream>>>(agg1, W1, b1, bufA);

  // layer 2
  k_agg256<<<(N_NODESC * 64 + 255) / 256, 256, 0, stream>>>(bufA, offs, ind, csr,
                                                            onorm, inorm, aggh, aggl);
  k_gemm_mfma<<<dim3((N_NODESC + 127) / 128, 2), 256, 0, stream>>>(aggh, aggl, Wth2,
                                                                   Wtl2, b2, bufA,
                                                                   N_NODESC);
  // layer 3
  k_agg256<<<(N_NODESC * 64 + 255) / 256, 256, 0, stream>>>(bufA, offs, ind, csr,
                                                            onorm, inorm, aggh, aggl);
  k_gemm_mfma<<<dim3((N_NODESC + 127) / 128, 2), 256, 0, stream>>>(aggh, aggl, Wth3,
                                                                   Wtl3, b3, bufA,
                                                                   N_NODESC);

  // readout + predictor
  int rwaves = (N_NODESC + RCHUNK - 1) / RCHUNK;
  k_readout<<<(rwaves * 64 + 255) / 256, 256, 0, stream>>>(bufA, gids, w_atom, b_atom,
                                                           out, mkeys);
  k_finalize<<<(N_GRAPHSC * HID + 255) / 256, 256, 0, stream>>>(mkeys, out);
  k_pred<<<N_GRAPHSC / 16, 256, 0, stream>>>(out, P1, pb1, P2, pb2,
                                             out + (size_t)N_GRAPHSC * 512);
}

// Round 13
// 631.187 us; speedup vs baseline: 2.4709x; 1.1701x over previous
//
#include <hip/hip_runtime.h>

#define N_NODESC 100000
#define N_EDGESC 300000
#define N_GRAPHSC 4000
#define IN_F 16
#define HID 256
#define RCHUNK 32

typedef __attribute__((ext_vector_type(8))) short short8v;   // 8 bf16 (4 VGPRs)
typedef __attribute__((ext_vector_type(4))) float f32x4;     // 4 fp32

// bf16 round-to-nearest-even, returned as fp32-aligned high bits
__device__ __forceinline__ unsigned bf16rne(float v) {
  unsigned u = __float_as_uint(v);
  return (u + 0x7fffu + ((u >> 16) & 1u)) & 0xffff0000u;
}

// ---------------- degree / norm / CSR build ----------------

__global__ __launch_bounds__(256) void k_degrees(const int* __restrict__ src,
                                                 const int* __restrict__ dst,
                                                 int* __restrict__ outd,
                                                 int* __restrict__ ind) {
  int e = blockIdx.x * blockDim.x + threadIdx.x;
  if (e < N_EDGESC) {
    atomicAdd(&outd[src[e]], 1);
    atomicAdd(&ind[dst[e]], 1);
  }
}

__global__ __launch_bounds__(256) void k_norms(const int* __restrict__ outd,
                                               const int* __restrict__ ind,
                                               float* __restrict__ onorm,
                                               float* __restrict__ inorm) {
  int i = blockIdx.x * blockDim.x + threadIdx.x;
  if (i < N_NODESC) {
    onorm[i] = rsqrtf((float)max(outd[i], 1));
    inorm[i] = rsqrtf((float)max(ind[i], 1));
  }
}

// Parallel CSR offset assignment (round-12: replaced 161us serial scan, verified).
// Regions need only be DISJOINT, not ordered: block-local LDS scan + one
// atomicAdd per block for the base. Consumers use offs[i] + ind[i] as the end.
__global__ __launch_bounds__(256) void k_offs(const int* __restrict__ ind,
                                              int* __restrict__ offs,
                                              int* __restrict__ total) {
  __shared__ int sh[256];
  __shared__ int base;
  int t = threadIdx.x;
  int i = blockIdx.x * 256 + t;
  int v = (i < N_NODESC) ? ind[i] : 0;
  sh[t] = v;
  __syncthreads();
  for (int o = 1; o < 256; o <<= 1) {
    int x = (t >= o) ? sh[t - o] : 0;
    __syncthreads();
    sh[t] += x;
    __syncthreads();
  }
  if (t == 255) base = atomicAdd(total, sh[255]);
  __syncthreads();
  if (i < N_NODESC) offs[i] = base + sh[t] - v;  // exclusive local prefix + base
}

__global__ __launch_bounds__(256) void k_fill(const int* __restrict__ src,
                                              const int* __restrict__ dst,
                                              const int* __restrict__ offs,
                                              int* __restrict__ cursor,
                                              int* __restrict__ csr) {
  int e = blockIdx.x * blockDim.x + threadIdx.x;
  if (e < N_EDGESC) {
    int d = dst[e];
    int p = offs[d] + atomicAdd(&cursor[d], 1);
    csr[p] = src[e];
  }
}

// ---------------- layer 1: 16-d aggregation + 16x256 matmul ----------------

__global__ __launch_bounds__(256) void k_agg16(const float* __restrict__ feats,
                                               const int* __restrict__ offs,
                                               const int* __restrict__ ind,
                                               const int* __restrict__ csr,
                                               const float* __restrict__ onorm,
                                               const float* __restrict__ inorm,
                                               float* __restrict__ agg1) {
  int gid = blockIdx.x * blockDim.x + threadIdx.x;
  int node = gid >> 4;
  if (node >= N_NODESC) return;
  int f = gid & 15;
  int b = offs[node], e = b + ind[node];
  float acc = 0.f;
  for (int k = b; k < e; ++k) {
    int s = csr[k];
    acc = fmaf(feats[s * IN_F + f], onorm[s], acc);
  }
  agg1[(size_t)node * IN_F + f] = acc * inorm[node];
}

__global__ __launch_bounds__(256) void k_mm16(const float* __restrict__ agg1,
                                              const float* __restrict__ W,
                                              const float* __restrict__ bias,
                                              float* __restrict__ out) {
  __shared__ float Ws[IN_F * HID];
  __shared__ float bs[HID];
  int t = threadIdx.x;
  for (int i = t; i < IN_F * HID; i += 256) Ws[i] = W[i];
  bs[t] = bias[t];
  __syncthreads();
  for (int node = blockIdx.x; node < N_NODESC; node += gridDim.x) {
    float a[IN_F];
#pragma unroll
    for (int k = 0; k < IN_F; ++k) a[k] = agg1[(size_t)node * IN_F + k];
    float acc = bs[t];
#pragma unroll
    for (int k = 0; k < IN_F; ++k) acc = fmaf(a[k], Ws[k * HID + t], acc);
    out[(size_t)node * HID + t] = acc;
  }
}

// ---------------- 256-d aggregation: one wave per node, bf16-split output ----------------

__global__ __launch_bounds__(256) void k_agg256(const float* __restrict__ h,
                                                const int* __restrict__ offs,
                                                const int* __restrict__ ind,
                                                const int* __restrict__ csr,
                                                const float* __restrict__ onorm,
                                                const float* __restrict__ inorm,
                                                short* __restrict__ aggh,
                                                short* __restrict__ aggl) {
  int wid = (int)((blockIdx.x * (size_t)blockDim.x + threadIdx.x) >> 6);
  int lane = threadIdx.x & 63;
  if (wid >= N_NODESC) return;
  int b = offs[wid], e = b + ind[wid];
  const float4* hp = (const float4*)h;
  float4 acc = make_float4(0.f, 0.f, 0.f, 0.f);
  for (int k = b; k < e; ++k) {
    int s = csr[k];
    float w = onorm[s];
    float4 v = hp[(size_t)s * 64 + lane];
    acc.x = fmaf(v.x, w, acc.x);
    acc.y = fmaf(v.y, w, acc.y);
    acc.z = fmaf(v.z, w, acc.z);
    acc.w = fmaf(v.w, w, acc.w);
  }
  float wi = inorm[wid];
  float v[4] = {acc.x * wi, acc.y * wi, acc.z * wi, acc.w * wi};
  unsigned hb[4], lb[4];
#pragma unroll
  for (int j = 0; j < 4; ++j) {
    hb[j] = bf16rne(v[j]);
    float res = v[j] - __uint_as_float(hb[j]);
    lb[j] = bf16rne(res);
  }
  uint2 ph = make_uint2((hb[0] >> 16) | hb[1], (hb[2] >> 16) | hb[3]);
  uint2 pl = make_uint2((lb[0] >> 16) | lb[1], (lb[2] >> 16) | lb[3]);
  ((uint2*)aggh)[(size_t)wid * 64 + lane] = ph;
  ((uint2*)aggl)[(size_t)wid * 64 + lane] = pl;
}

// ---------------- W transpose + bf16 split: Wt[n][k] ----------------

__global__ __launch_bounds__(256) void k_wsplit(const float* __restrict__ W,
                                                short* __restrict__ Wth,
                                                short* __restrict__ Wtl) {
  int i = blockIdx.x * blockDim.x + threadIdx.x;  // i = k*256 + n
  if (i >= HID * HID) return;
  int k = i >> 8, n = i & 255;
  float v = W[i];
  unsigned hb = bf16rne(v);
  float res = v - __uint_as_float(hb);
  unsigned lb = bf16rne(res);
  Wth[(size_t)n * HID + k] = (short)(hb >> 16);
  Wtl[(size_t)n * HID + k] = (short)(lb >> 16);
}

// ---------------- MFMA GEMM: C[M x 256] = A @ W + bias, split-bf16 x3 ----------------
// Round-12 counters: 160us, VGPR=76, MfmaUtil 9.6%, all pipes <17% -> latency-bound
// on W-loads (each wave streams 128KB of W from L2 with shallow MLP, 4x redundant
// per block). This round: LDS-stage W per 128-wide K-chunk (64 KB, 2 blocks/CU),
// 512 threads / 8 waves per block (256 rows x 128 cols), XOR-swizzled 16B slots
// (slot ^= row&15) for conflict-free ds_read_b128. A-loads stay global (hidden by
// 4 waves/SIMD TLP + MFMA). acc[2][8] fully unrolled (rule #20). Fragment layouts
// HW-verified (rounds 3/8/10/12):
//   A: lane l holds A[l&15][8*(l>>4)+e]  (b128 load)
//   B: lane l holds B[8*(l>>4)+e][l&15]  <- Wt[n][k] row-contiguous
//   C/D: col = lane&15, row = (lane>>4)*4 + reg

__global__ __launch_bounds__(512) void k_gemm_mfma(
    const short* __restrict__ Ah, const short* __restrict__ Al,
    const short* __restrict__ Wth, const short* __restrict__ Wtl,
    const float* __restrict__ bias, float* __restrict__ C, int M) {
  __shared__ short Wh[128 * 128];  // [row][swizzled 16B slot], one 128-K chunk
  __shared__ short Wl[128 * 128];
  int t = threadIdx.x;
  int wave = t >> 6, lane = t & 63;
  int m0 = blockIdx.x * 256 + wave * 32;
  int bn = blockIdx.y * 128;
  int lr = lane & 15;
  int g4 = lane >> 4;        // 0..3
  int lk = g4 * 8;

  f32x4 acc[2][8];
#pragma unroll
  for (int mf = 0; mf < 2; ++mf)
#pragma unroll
    for (int nf = 0; nf < 8; ++nf) acc[mf][nf] = (f32x4){0.f, 0.f, 0.f, 0.f};

  int row0 = min(m0 + lr, M - 1);       // clamp: loads safe, writes guarded below
  int row1 = min(m0 + 16 + lr, M - 1);
  const short* a0hp = Ah + (size_t)row0 * HID;
  const short* a0lp = Al + (size_t)row0 * HID;
  const short* a1hp = Ah + (size_t)row1 * HID;
  const short* a1lp = Al + (size_t)row1 * HID;

  // staging roles (fixed per thread)
  int su = t & 255;
  int srow = su >> 1;          // 0..127
  int shalf = su & 1;          // 0/1 -> k-offset 0/64 shorts
  const short* sgsrc = (t < 256) ? Wth : Wtl;
  short* sldst = (t < 256) ? Wh : Wl;

  for (int kc = 0; kc < 2; ++kc) {
    // ---- stage W chunk [bn..bn+128) x [kc*128..kc*128+128) into LDS ----
    {
      const short8v* g =
          (const short8v*)(sgsrc + (size_t)(bn + srow) * HID + kc * 128 + shalf * 64);
#pragma unroll
      for (int j = 0; j < 8; ++j) {
        int slot = shalf * 8 + j;            // 0..15 (16B slots per row)
        int sw = slot ^ (srow & 15);         // bank swizzle
        *(short8v*)(sldst + srow * 128 + sw * 8) = g[j];
      }
    }
    __syncthreads();

    // ---- compute 4 K-steps from LDS ----
#pragma unroll
    for (int k0 = 0; k0 < 4; ++k0) {
      int gk = kc * 128 + k0 * 32 + lk;
      short8v ah0 = *(const short8v*)(a0hp + gk);
      short8v al0 = *(const short8v*)(a0lp + gk);
      short8v ah1 = *(const short8v*)(a1hp + gk);
      short8v al1 = *(const short8v*)(a1lp + gk);
      int sw = ((k0 * 4 + g4) ^ lr) * 8;     // swizzled slot (shorts offset)
#pragma unroll
      for (int nf = 0; nf < 8; ++nf) {
        int r = nf * 16 + lr;
        short8v wh = *(const short8v*)(Wh + r * 128 + sw);
        short8v wl = *(const short8v*)(Wl + r * 128 + sw);
        acc[0][nf] = __builtin_amdgcn_mfma_f32_16x16x32_bf16(ah0, wh, acc[0][nf], 0, 0, 0);
        acc[0][nf] = __builtin_amdgcn_mfma_f32_16x16x32_bf16(al0, wh, acc[0][nf], 0, 0, 0);
        acc[0][nf] = __builtin_amdgcn_mfma_f32_16x16x32_bf16(ah0, wl, acc[0][nf], 0, 0, 0);
        acc[1][nf] = __builtin_amdgcn_mfma_f32_16x16x32_bf16(ah1, wh, acc[1][nf], 0, 0, 0);
        acc[1][nf] = __builtin_amdgcn_mfma_f32_16x16x32_bf16(al1, wh, acc[1][nf], 0, 0, 0);
        acc[1][nf] = __builtin_amdgcn_mfma_f32_16x16x32_bf16(ah1, wl, acc[1][nf], 0, 0, 0);
      }
    }
    __syncthreads();
  }

  int cr = g4 * 4;
#pragma unroll
  for (int mf = 0; mf < 2; ++mf) {
#pragma unroll
    for (int nf = 0; nf < 8; ++nf) {
      float bv = bias[bn + nf * 16 + lr];
      f32x4 v = acc[mf][nf];
#pragma unroll
      for (int r = 0; r < 4; ++r) {
        int row = m0 + mf * 16 + cr + r;
        if (row < M) C[(size_t)row * HID + bn + nf * 16 + lr] = v[r] + bv;
      }
    }
  }
}

// ---------------- readout: sigmoid-weighted sum + segment max ----------------

__device__ __forceinline__ unsigned fkey(float f) {
  unsigned u = __float_as_uint(f);
  return (u & 0x80000000u) ? ~u : (u | 0x80000000u);
}

__device__ __forceinline__ void flush_group(int g, int lane, const float4& s,
                                            const uint4& mk, float* __restrict__ out,
                                            unsigned* __restrict__ mkeys) {
  float* hp = out + (size_t)g * 512 + (lane << 2);
  atomicAdd(hp + 0, s.x);
  atomicAdd(hp + 1, s.y);
  atomicAdd(hp + 2, s.z);
  atomicAdd(hp + 3, s.w);
  unsigned* mp = mkeys + ((size_t)g << 8) + (lane << 2);
  atomicMax(mp + 0, mk.x);
  atomicMax(mp + 1, mk.y);
  atomicMax(mp + 2, mk.z);
  atomicMax(mp + 3, mk.w);
}

__global__ __launch_bounds__(256) void k_readout(const float* __restrict__ h,
                                                 const int* __restrict__ gids,
                                                 const float* __restrict__ w_atom,
                                                 const float* __restrict__ b_atom,
                                                 float* __restrict__ out,
                                                 unsigned* __restrict__ mkeys) {
  int wid = (int)((blockIdx.x * (size_t)blockDim.x + threadIdx.x) >> 6);
  int lane = threadIdx.x & 63;
  int n0 = wid * RCHUNK;
  if (n0 >= N_NODESC) return;
  int n1 = min(n0 + RCHUNK, N_NODESC);
  float4 wa = ((const float4*)w_atom)[lane];
  float ba = b_atom[0];
  float4 s = make_float4(0.f, 0.f, 0.f, 0.f);
  uint4 mk = make_uint4(0u, 0u, 0u, 0u);
  int cur = gids[n0];
  for (int i = n0; i < n1; ++i) {
    int g = gids[i];
    if (g != cur) {
      flush_group(cur, lane, s, mk, out, mkeys);
      s = make_float4(0.f, 0.f, 0.f, 0.f);
      mk = make_uint4(0u, 0u, 0u, 0u);
      cur = g;
    }
    float4 v = ((const float4*)h)[(size_t)i * 64 + lane];
    float d = fmaf(v.x, wa.x, fmaf(v.y, wa.y, fmaf(v.z, wa.z, v.w * wa.w)));
#pragma unroll
    for (int o = 32; o > 0; o >>= 1) d += __shfl_xor(d, o, 64);
    float wgt = 1.0f / (1.0f + expf(-(d + ba)));
    s.x = fmaf(v.x, wgt, s.x);
    s.y = fmaf(v.y, wgt, s.y);
    s.z = fmaf(v.z, wgt, s.z);
    s.w = fmaf(v.w, wgt, s.w);
    mk.x = max(mk.x, fkey(v.x));
    mk.y = max(mk.y, fkey(v.y));
    mk.z = max(mk.z, fkey(v.z));
    mk.w = max(mk.w, fkey(v.w));
  }
  flush_group(cur, lane, s, mk, out, mkeys);
}

__global__ __launch_bounds__(256) void k_finalize(const unsigned* __restrict__ mkeys,
                                                  float* __restrict__ out) {
  int i = blockIdx.x * blockDim.x + threadIdx.x;
  if (i >= N_GRAPHSC * HID) return;
  int g = i >> 8, c = i & 255;
  unsigned k = mkeys[i];
  float f = 0.0f;
  if (k != 0u) f = (k & 0x80000000u) ? __uint_as_float(k ^ 0x80000000u) : __uint_as_float(~k);
  out[(size_t)g * 512 + 256 + c] = f;
}

// ---------------- predictor MLP ----------------

__global__ __launch_bounds__(256) void k_pred(const float* __restrict__ hg,
                                              const float* __restrict__ P1,
                                              const float* __restrict__ pb1,
                                              const float* __restrict__ P2,
                                              const float* __restrict__ pb2,
                                              float* __restrict__ pred) {
  __shared__ float P1s[32 * 256];
  __shared__ float hgt[32 * 16];
  int t = threadIdx.x;
  int g0 = blockIdx.x * 16;
  int tx = t & 63;
  int tg = t >> 6;
  float acc[4][4];
#pragma unroll
  for (int a = 0; a < 4; ++a)
#pragma unroll
    for (int b = 0; b < 4; ++b) acc[a][b] = 0.f;

  for (int kc = 0; kc < 512; kc += 32) {
    const float4* srcp = (const float4*)(P1 + (size_t)kc * 256);
    float4* dstp = (float4*)P1s;
    for (int i = t; i < 2048; i += 256) dstp[i] = srcp[i];
    {
      int g = t & 15, kk = t >> 4;
      const float* hrow = hg + (size_t)(g0 + g) * 512 + kc;
#pragma unroll
      for (int j = 0; j < 2; ++j) hgt[(kk * 2 + j) * 16 + g] = hrow[kk * 2 + j];
    }
    __syncthreads();
#pragma unroll 8
    for (int k = 0; k < 32; ++k) {
      float4 pv = *(const float4*)&P1s[k * 256 + (tx << 2)];
      float4 hv = *(const float4*)&hgt[(k << 4) + (tg << 2)];
      acc[0][0] = fmaf(hv.x, pv.x, acc[0][0]);
      acc[0][1] = fmaf(hv.x, pv.y, acc[0][1]);
      acc[0][2] = fmaf(hv.x, pv.z, acc[0][2]);
      acc[0][3] = fmaf(hv.x, pv.w, acc[0][3]);
      acc[1][0] = fmaf(hv.y, pv.x, acc[1][0]);
      acc[1][1] = fmaf(hv.y, pv.y, acc[1][1]);
      acc[1][2] = fmaf(hv.y, pv.z, acc[1][2]);
      acc[1][3] = fmaf(hv.y, pv.w, acc[1][3]);
      acc[2][0] = fmaf(hv.z, pv.x, acc[2][0]);
      acc[2][1] = fmaf(hv.z, pv.y, acc[2][1]);
      acc[2][2] = fmaf(hv.z, pv.z, acc[2][2]);
      acc[2][3] = fmaf(hv.z, pv.w, acc[2][3]);
      acc[3][0] = fmaf(hv.w, pv.x, acc[3][0]);
      acc[3][1] = fmaf(hv.w, pv.y, acc[3][1]);
      acc[3][2] = fmaf(hv.w, pv.z, acc[3][2]);
      acc[3][3] = fmaf(hv.w, pv.w, acc[3][3]);
    }
    __syncthreads();
  }

  float4 b1v = *(const float4*)(pb1 + (tx << 2));
  float4 p2v = *(const float4*)(P2 + (tx << 2));
  float pb2v = pb2[0];
#pragma unroll
  for (int g = 0; g < 4; ++g) {
    float r = fmaxf(acc[g][0] + b1v.x, 0.f) * p2v.x +
              fmaxf(acc[g][1] + b1v.y, 0.f) * p2v.y +
              fmaxf(acc[g][2] + b1v.z, 0.f) * p2v.z +
              fmaxf(acc[g][3] + b1v.w, 0.f) * p2v.w;
#pragma unroll
    for (int o = 32; o > 0; o >>= 1) r += __shfl_xor(r, o, 64);
    if (tx == 0) pred[g0 + (tg << 2) + g] = r + pb2v;
  }
}

// ---------------- host orchestration ----------------

extern "C" void kernel_launch(void* const* d_in, const int* in_sizes, int n_in,
                              void* d_out, int out_size, void* d_ws, size_t ws_size,
                              hipStream_t stream) {
  const float* feats = (const float*)d_in[0];
  const int* src = (const int*)d_in[1];
  const int* dst = (const int*)d_in[2];
  const int* gids = (const int*)d_in[3];
  const float* W1 = (const float*)d_in[4];
  const float* b1 = (const float*)d_in[5];
  const float* W2 = (const float*)d_in[6];
  const float* b2 = (const float*)d_in[7];
  const float* W3 = (const float*)d_in[8];
  const float* b3 = (const float*)d_in[9];
  const float* w_atom = (const float*)d_in[10];
  const float* b_atom = (const float*)d_in[11];
  const float* P1 = (const float*)d_in[12];
  const float* pb1 = (const float*)d_in[13];
  const float* P2 = (const float*)d_in[14];
  const float* pb2 = (const float*)d_in[15];
  float* out = (float*)d_out;

  char* base = (char*)d_ws;
  size_t off = 0;
  auto alloc = [&](size_t bytes) -> void* {
    void* p = base + off;
    off = (off + bytes + 511) & ~(size_t)511;
    return p;
  };
  int* outd = (int*)alloc((size_t)N_NODESC * 4);
  int* ind = (int*)alloc((size_t)N_NODESC * 4);
  float* onorm = (float*)alloc((size_t)N_NODESC * 4);
  float* inorm = (float*)alloc((size_t)N_NODESC * 4);
  int* offs = (int*)alloc((size_t)(N_NODESC + 1) * 4);
  int* cursor = (int*)alloc((size_t)N_NODESC * 4);
  int* total = (int*)alloc(4);
  int* csr = (int*)alloc((size_t)N_EDGESC * 4);
  float* agg1 = (float*)alloc((size_t)N_NODESC * IN_F * 4);
  float* bufA = (float*)alloc((size_t)N_NODESC * HID * 4);
  short* aggh = (short*)alloc((size_t)N_NODESC * HID * 2);
  short* aggl = (short*)alloc((size_t)N_NODESC * HID * 2);
  short* Wth2 = (short*)alloc((size_t)HID * HID * 2);
  short* Wtl2 = (short*)alloc((size_t)HID * HID * 2);
  short* Wth3 = (short*)alloc((size_t)HID * HID * 2);
  short* Wtl3 = (short*)alloc((size_t)HID * HID * 2);
  unsigned* mkeys = (unsigned*)alloc((size_t)N_GRAPHSC * HID * 4);

  hipMemsetAsync(outd, 0, (size_t)N_NODESC * 4, stream);
  hipMemsetAsync(ind, 0, (size_t)N_NODESC * 4, stream);
  hipMemsetAsync(cursor, 0, (size_t)N_NODESC * 4, stream);
  hipMemsetAsync(total, 0, 4, stream);
  hipMemsetAsync(mkeys, 0, (size_t)N_GRAPHSC * HID * 4, stream);
  hipMemsetAsync(out, 0, (size_t)out_size * 4, stream);

  k_degrees<<<(N_EDGESC + 255) / 256, 256, 0, stream>>>(src, dst, outd, ind);
  k_norms<<<(N_NODESC + 255) / 256, 256, 0, stream>>>(outd, ind, onorm, inorm);
  k_offs<<<(N_NODESC + 255) / 256, 256, 0, stream>>>(ind, offs, total);
  k_fill<<<(N_EDGESC + 255) / 256, 256, 0, stream>>>(src, dst, offs, cursor, csr);

  // W splits (independent of graph pipeline)
  k_wsplit<<<(HID * HID + 255) / 256, 256, 0, stream>>>(W2, Wth2, Wtl2);
  k_wsplit<<<(HID * HID + 255) / 256, 256, 0, stream>>>(W3, Wth3, Wtl3);

  // layer 1
  k_agg16<<<(N_NODESC * IN_F + 255) / 256, 256, 0, stream>>>(feats, offs, ind, csr,
                                                             onorm, inorm, agg1);
  k_mm16<<<2048, 256, 0, stream>>>(agg1, W1, b1, bufA);

  // layer 2
  k_agg256<<<(N_NODESC * 64 + 255) / 256, 256, 0, stream>>>(bufA, offs, ind, csr,
                                                            onorm, inorm, aggh, aggl);
  k_gemm_mfma<<<dim3((N_NODESC + 255) / 256, 2), 512, 0, stream>>>(aggh, aggl, Wth2,
                                                                   Wtl2, b2, bufA,
                                                                   N_NODESC);
  // layer 3
  k_agg256<<<(N_NODESC * 64 + 255) / 256, 256, 0, stream>>>(bufA, offs, ind, csr,
                                                            onorm, inorm, aggh, aggl);
  k_gemm_mfma<<<dim3((N_NODESC + 255) / 256, 2), 512, 0, stream>>>(aggh, aggl, Wth3,
                                                                   Wtl3, b3, bufA,
                                                                   N_NODESC);

  // readout + predictor
  int rwaves = (N_NODESC + RCHUNK - 1) / RCHUNK;
  k_readout<<<(rwaves * 64 + 255) / 256, 256, 0, stream>>>(bufA, gids, w_atom, b_atom,
                                                           out, mkeys);
  k_finalize<<<(N_GRAPHSC * HID + 255) / 256, 256, 0, stream>>>(mkeys, out);
  k_pred<<<N_GRAPHSC / 16, 256, 0, stream>>>(out, P1, pb1, P2, pb2,
                                             out + (size_t)N_GRAPHSC * 512);
}